// Round 6
// baseline (436.681 us; speedup 1.0000x reference)
//
#include <hip/hip_runtime.h>

// ---------------------------------------------------------------------------
// Wiener 3D patch filter, MI355X — register-resident FFT, interleaved-complex
// LDS, transposed-write passes (all LDS reads are linear ds_read_b128, all
// writes ds_write_b64).
// 4 patches / 256-thread block; 6 complex planes (32 x 32, row stride 68):
//   plane p (p=0..3): Z_p = fft2(a0_p + i*a1_p)   (later reused for Q_p)
//   plane 4+j (j=0,1): W_j = fft2(a2_{2j} + i*a2_{2j+1})  (reused for R_j)
// Overlap-add via 16 parity planes in d_ws (no atomics); atomic fallback.
// ---------------------------------------------------------------------------

constexpr float TWR[16] = {
  1.0f, 0.98078528040323044f, 0.92387953251128674f, 0.83146961230254524f,
  0.70710678118654752f, 0.55557023301960222f, 0.38268343236508977f, 0.19509032201612827f,
  0.0f, -0.19509032201612827f, -0.38268343236508977f, -0.55557023301960222f,
  -0.70710678118654752f, -0.83146961230254524f, -0.92387953251128674f, -0.98078528040323044f
};
constexpr float TWI[16] = {
  -0.0f, -0.19509032201612827f, -0.38268343236508977f, -0.55557023301960222f,
  -0.70710678118654752f, -0.83146961230254524f, -0.92387953251128674f, -0.98078528040323044f,
  -1.0f, -0.98078528040323044f, -0.92387953251128674f, -0.83146961230254524f,
  -0.70710678118654752f, -0.55557023301960222f, -0.38268343236508977f, -0.19509032201612827f
};
constexpr int REV5[32] = {0,16,8,24,4,20,12,28,2,18,10,26,6,22,14,30,
                          1,17,9,25,5,21,13,29,3,19,11,27,7,23,15,31};
// W1C[i] = exp(-(i-15.5)^2 / 76.8)
constexpr float W1C[32] = {
  0.0437942f, 0.0647235f, 0.0931963f, 0.1307451f,
  0.1787074f, 0.2379852f, 0.3087788f, 0.3903331f,
  0.4807436f, 0.5768747f, 0.6744349f, 0.7682257f,
  0.8525655f, 0.9218431f, 0.9711281f, 0.9967501f,
  0.9967501f, 0.9711281f, 0.9218431f, 0.8525655f,
  0.7682257f, 0.6744349f, 0.5768747f, 0.4807436f,
  0.3903331f, 0.3087788f, 0.2379852f, 0.1787074f,
  0.1307451f, 0.0931963f, 0.0647235f, 0.0437942f
};

constexpr float S3    = 0.86602540378443865f;  // sqrt(3)/2
constexpr float EPSF  = 1e-15f;
constexpr float INV_WIN_DEN = -1.0f / 76.8f;
constexpr float CS    = 1.1499041e-4f;         // (mean win^2)^2 / 1024
constexpr float INV6144 = 1.0f / 6144.0f;

#define PLANE_FLOATS (4 * 3 * 512 * 512)
#define WS_NEEDED    ((size_t)16 * PLANE_FLOATS * 4)
#define CSTR 68                 // complex row stride in floats (32 complex + pad)
#define PL   (32 * CSTR)        // plane size in floats = 2176

// ---- butterfly with compile-time twiddle specialization ----
template<int SIGN, int K>
__device__ __forceinline__ void bfly(float& ur, float& ui, float& vr, float& vi) {
  if constexpr (K == 0) {
    float tr = vr, ti = vi;
    vr = ur - tr; vi = ui - ti; ur += tr; ui += ti;
  } else if constexpr (K == 8) {
    float tr = (SIGN < 0) ?  vi : -vi;
    float ti = (SIGN < 0) ? -vr :  vr;
    vr = ur - tr; vi = ui - ti; ur += tr; ui += ti;
  } else {
    constexpr float wr = TWR[K];
    constexpr float wi = (SIGN < 0) ? TWI[K] : -TWI[K];
    float tr = wr * vr - wi * vi;
    float ti = wr * vi + wi * vr;
    vr = ur - tr; vi = ui - ti; ur += tr; ui += ti;
  }
}

template<int SIGN, int S, int J>
__device__ __forceinline__ void stage_j(float* ar, float* ai) {
  constexpr int m = 1 << S, h = m >> 1, ts = 32 >> S;
  if constexpr (J < h) {
    #pragma unroll
    for (int k = 0; k < 32; k += m)
      bfly<SIGN, J * ts>(ar[k + J], ai[k + J], ar[k + J + h], ai[k + J + h]);
    stage_j<SIGN, S, J + 1>(ar, ai);
  }
}

template<int SIGN>
__device__ __forceinline__ void fft32(float* ar, float* ai) {
  stage_j<SIGN, 1, 0>(ar, ai);
  stage_j<SIGN, 2, 0>(ar, ai);
  stage_j<SIGN, 3, 0>(ar, ai);
  stage_j<SIGN, 4, 0>(ar, ai);
  stage_j<SIGN, 5, 0>(ar, ai);
}

// reflect-pad index mapping, N=512, mode='reflect'
__device__ __forceinline__ int refl(int v) {
  v = (v < 0) ? -v : v;
  return (v >= 512) ? (1022 - v) : v;
}

// load 32 floats of one padded row into registers
__device__ __forceinline__ void load_row(const float* __restrict__ plane,
                                         int ry, int gx0, float* v) {
  const float* rp = plane + (size_t)ry * 512;
  if (gx0 >= 0 && gx0 <= 480) {
    const float4* r4 = reinterpret_cast<const float4*>(rp + gx0);
    #pragma unroll
    for (int c = 0; c < 8; ++c) {
      const float4 f = r4[c];
      v[4*c+0] = f.x; v[4*c+1] = f.y; v[4*c+2] = f.z; v[4*c+3] = f.w;
    }
  } else {
    #pragma unroll
    for (int i = 0; i < 32; ++i) v[i] = rp[refl(gx0 + i)];
  }
}

// MODE 0: atomicAdd into out (fallback).  MODE 1: plain store into parity plane.
template<int MODE>
__global__ __launch_bounds__(256)
void wiener_patch(const float* __restrict__ I,
                  const float* __restrict__ Sd,
                  float* __restrict__ dst)
{
  __shared__ __align__(16) float sc[6 * PL];
  __shared__ float red[12];      // std sums: [patch*3 + ch]

  const int t    = threadIdx.x;
  const int T    = t >> 5;       // transform/plane id 0..5 (t<192), else idle
  const int line = t & 31;

  // persistent per-thread state (valid for t<192)
  int pyA = 0, pxA = 0, bA = 0, pyB = 0, pxB = 0, bB = 0;
  float mA = 0.f, mB = 0.f, wrow = 0.f;

  // ================= pass 1: global -> regs, fwd FFT over x ================
  if (t < 192) {
    int PA, PB, chA, chB, redA, redB;
    if (T < 4) {
      PA = blockIdx.x * 4 + T;  PB = PA;
      chA = 0; chB = 1; redA = T * 3 + 0; redB = T * 3 + 1;
    } else {
      const int j = T - 4;
      PA = blockIdx.x * 4 + 2 * j;  PB = PA + 1;
      chA = 2; chB = 2; redA = (2*j) * 3 + 2; redB = (2*j+1) * 3 + 2;
    }
    int pp = PA; pxA = pp % 67 + 1; pp /= 67; pyA = pp % 67 + 1; bA = pp / 67;
    pp = PB;     pxB = pp % 67 + 1; pp /= 67; pyB = pp % 67 + 1; bB = pp / 67;

    const int ryA = refl(pyA * 8 - 32 + line), gxA = pxA * 8 - 32;
    const int ryB = refl(pyB * 8 - 32 + line), gxB = pxB * 8 - 32;
    const float* IA = I  + ((size_t)bA * 3 + chA) * 262144;
    const float* IB = I  + ((size_t)bB * 3 + chB) * 262144;
    const float* SA = Sd + ((size_t)bA * 3 + chA) * 262144;
    const float* SB = Sd + ((size_t)bB * 3 + chB) * 262144;

    float va[32], vb[32], vt[32];
    load_row(IA, ryA, gxA, va);
    load_row(IB, ryB, gxB, vb);
    float sa = 0.f, sb = 0.f;
    #pragma unroll
    for (int i = 0; i < 32; ++i) { sa += va[i]; sb += vb[i]; }
    load_row(SA, ryA, gxA, vt);
    float ssa = 0.f;
    #pragma unroll
    for (int i = 0; i < 32; ++i) ssa += vt[i];
    load_row(SB, ryB, gxB, vt);
    float ssb = 0.f;
    #pragma unroll
    for (int i = 0; i < 32; ++i) ssb += vt[i];

    // reduce over the 32 lanes of this half-wave
    #pragma unroll
    for (int m = 1; m <= 16; m <<= 1) {
      sa  += __shfl_xor(sa,  m);
      sb  += __shfl_xor(sb,  m);
      ssa += __shfl_xor(ssa, m);
      ssb += __shfl_xor(ssb, m);
    }
    mA = sa * (1.f / 1024.f);
    mB = sb * (1.f / 1024.f);
    if (line == 0) { red[redA] = ssa; red[redB] = ssb; }

    const float ty = (float)line - 15.5f;
    wrow = __expf(ty * ty * INV_WIN_DEN);
    const float hw = 0.5f * wrow;                 // 0.5 folds Hermitian split

    float ar[32], ai[32];
    #pragma unroll
    for (int i = 0; i < 32; ++i) {
      const int s = REV5[i];
      const float wv = hw * W1C[s];
      ar[i] = (va[s] - mA) * wv;
      ai[i] = (vb[s] - mB) * wv;
    }
    fft32<-1>(ar, ai);
    // write transposed: [kx][y]
    const int wb = T * PL + 2 * line;
    #pragma unroll
    for (int kx = 0; kx < 32; ++kx)
      *reinterpret_cast<float2*>(&sc[wb + kx * CSTR]) = make_float2(ar[kx], ai[kx]);
  }
  __syncthreads();

  // ================= pass 2: fwd FFT over y ================================
  {
    float nr[32], ni[32];
    if (t < 192) {
      const float4* p4 = reinterpret_cast<const float4*>(&sc[T * PL + line * CSTR]);
      #pragma unroll
      for (int c = 0; c < 16; ++c) {
        const float4 f = p4[c];
        nr[2*c] = f.x; ni[2*c] = f.y; nr[2*c+1] = f.z; ni[2*c+1] = f.w;
      }
    }
    __syncthreads();            // all reads done before transposed writes
    if (t < 192) {
      float ar[32], ai[32];
      #pragma unroll
      for (int i = 0; i < 32; ++i) { ar[i] = nr[REV5[i]]; ai[i] = ni[REV5[i]]; }
      fft32<-1>(ar, ai);
      const int wb = T * PL + 2 * line;   // line = kx; write [ky][kx]
      #pragma unroll
      for (int ky = 0; ky < 32; ++ky)
        *reinterpret_cast<float2*>(&sc[wb + ky * CSTR]) = make_float2(ar[ky], ai[ky]);
    }
  }
  __syncthreads();

  // ================= spectral middle (mirror pairs) ========================
  for (int task = t; task < 1028; task += 256) {
    const int j = (task >= 514) ? 1 : 0;
    const int u = task - j * 514;
    int ky, kx;
    if (u < 480) { ky = u & 31; const int d = u >> 5; kx = 1 + (ky + d) % 15; }
    else { const int e = u - 480; kx = (e >= 17) ? 16 : 0; ky = (e >= 17) ? (e - 17) : e; }
    const int my = (32 - ky) & 31, mx = (32 - kx) & 31;
    const int ok = ky * CSTR + 2 * kx, om = my * CSTR + 2 * mx;
    const int zp0 = (2 * j) * PL, zp1 = zp0 + PL, wp = (4 + j) * PL;
    const float2 Wk = *reinterpret_cast<const float2*>(&sc[wp + ok]);
    const float2 Wm = *reinterpret_cast<const float2*>(&sc[wp + om]);
    float B2r[2], B2i[2];
    #pragma unroll
    for (int lp = 0; lp < 2; ++lp) {
      const int zp = lp ? zp1 : zp0;
      const float2 Zk = *reinterpret_cast<const float2*>(&sc[zp + ok]);
      const float2 Zm = *reinterpret_cast<const float2*>(&sc[zp + om]);
      // Hermitian splits (x2 true scale; 0.5 folded into forward window)
      const float F0r = Zk.x + Zm.x, F0i = Zk.y - Zm.y;
      const float F1r = Zk.y + Zm.y, F1i = Zm.x - Zk.x;
      const float F2r = lp ? (Wk.y + Wm.y) : (Wk.x + Wm.x);
      const float F2i = lp ? (Wm.x - Wk.x) : (Wk.y - Wm.y);
      // forward channel DFT
      const float Spr = F1r + F2r, Spi = F1i + F2i, Smr = F1r - F2r, Smi = F1i - F2i;
      const float A0r = F0r + Spr,        A0i = F0i + Spi;
      const float t1r = F0r - 0.5f * Spr, t1i = F0i - 0.5f * Spi;
      const float A1r = t1r + S3 * Smi,   A1i = t1i - S3 * Smr;
      const float A2r = t1r - S3 * Smi,   A2i = t1i + S3 * Smr;
      const float P0 = A0r * A0r + A0i * A0i + EPSF;
      const float P1 = A1r * A1r + A1i * A1i + EPSF;
      const float P2 = A2r * A2r + A2i * A2i + EPSF;
      const int p = 2 * j + lp;
      const float s0 = red[p*3+0], s1 = red[p*3+1], s2v = red[p*3+2];
      const float Pv0 = CS * s0 * s0, Pv1 = CS * s1 * s1, Pv2 = CS * s2v * s2v;
      const float rp0 = __builtin_amdgcn_rcpf(P0);
      const float rp1 = __builtin_amdgcn_rcpf(P1);
      const float rp2 = __builtin_amdgcn_rcpf(P2);
      const float H0  = fmaxf(P0 - Pv0, 0.f) * rp0;
      const float H1k = fmaxf(P1 - Pv1, 0.f) * rp1;
      const float H2k = fmaxf(P2 - Pv2, 0.f) * rp2;
      const float H1m = fmaxf(P2 - Pv1, 0.f) * rp2;   // mirror: P1(m)=P2(k)
      const float H2m = fmaxf(P1 - Pv2, 0.f) * rp1;   // mirror: P2(m)=P1(k)
      // k side
      float G0r = H0 * A0r,  G0i = H0 * A0i;
      float G1r = H1k * A1r, G1i = H1k * A1i;
      float G2r = H2k * A2r, G2i = H2k * A2i;
      float Qpr = G1r + G2r, Qpi = G1i + G2i, Qmr = G1r - G2r, Qmi = G1i - G2i;
      const float M0kr = G0r + Qpr,        M0ki = G0i + Qpi;
      float u1r = G0r - 0.5f * Qpr,        u1i = G0i - 0.5f * Qpi;
      const float M1kr = u1r - S3 * Qmi,   M1ki = u1i + S3 * Qmr;
      const float M2kr = u1r + S3 * Qmi,   M2ki = u1i - S3 * Qmr;
      // m side: A0->conj(A0), A1->conj(A2), A2->conj(A1)
      G0r = H0 * A0r;   G0i = -H0 * A0i;
      G1r = H1m * A2r;  G1i = -H1m * A2i;
      G2r = H2m * A1r;  G2i = -H2m * A1i;
      Qpr = G1r + G2r;  Qpi = G1i + G2i;  Qmr = G1r - G2r;  Qmi = G1i - G2i;
      const float M0mr = G0r + Qpr,        M0mi = G0i + Qpi;
      u1r = G0r - 0.5f * Qpr;              u1i = G0i - 0.5f * Qpi;
      const float M1mr = u1r - S3 * Qmi,   M1mi = u1i + S3 * Qmr;
      const float M2mr = u1r + S3 * Qmi,   M2mi = u1i - S3 * Qmr;
      // Hermitian parts x2 (1/2 folded into epilogue 1/6144)
      const float B0r = M0kr + M0mr, B0i = M0ki - M0mi;
      const float B1r = M1kr + M1mr, B1i = M1ki - M1mi;
      B2r[lp] = M2kr + M2mr;  B2i[lp] = M2ki - M2mi;
      // pack Q = H0 + i*H1 over Z plane
      *reinterpret_cast<float2*>(&sc[zp + ok]) = make_float2(B0r - B1i, B0i + B1r);
      *reinterpret_cast<float2*>(&sc[zp + om]) = make_float2(B0r + B1i, B1r - B0i);
    }
    // pack R = H2_{p0} + i*H2_{p1} over W plane
    *reinterpret_cast<float2*>(&sc[wp + ok]) = make_float2(B2r[0] - B2i[1], B2i[0] + B2r[1]);
    *reinterpret_cast<float2*>(&sc[wp + om]) = make_float2(B2r[0] + B2i[1], B2r[1] - B2i[0]);
  }
  __syncthreads();

  // ================= pass 3: inv FFT over kx ===============================
  {
    float nr[32], ni[32];
    if (t < 192) {
      const float4* p4 = reinterpret_cast<const float4*>(&sc[T * PL + line * CSTR]);
      #pragma unroll
      for (int c = 0; c < 16; ++c) {
        const float4 f = p4[c];
        nr[2*c] = f.x; ni[2*c] = f.y; nr[2*c+1] = f.z; ni[2*c+1] = f.w;
      }
    }
    __syncthreads();
    if (t < 192) {
      float ar[32], ai[32];
      #pragma unroll
      for (int i = 0; i < 32; ++i) { ar[i] = nr[REV5[i]]; ai[i] = ni[REV5[i]]; }
      fft32<+1>(ar, ai);
      const int wb = T * PL + 2 * line;   // line = ky; write [x][ky]
      #pragma unroll
      for (int x = 0; x < 32; ++x)
        *reinterpret_cast<float2*>(&sc[wb + x * CSTR]) = make_float2(ar[x], ai[x]);
    }
  }
  __syncthreads();

  // ================= pass 4: inv FFT over ky + epilogue from regs ==========
  if (t < 192) {
    float nr[32], ni[32];
    const float4* p4 = reinterpret_cast<const float4*>(&sc[T * PL + line * CSTR]);
    #pragma unroll
    for (int c = 0; c < 16; ++c) {
      const float4 f = p4[c];
      nr[2*c] = f.x; ni[2*c] = f.y; nr[2*c+1] = f.z; ni[2*c+1] = f.w;
    }
    float ar[32], ai[32];
    #pragma unroll
    for (int i = 0; i < 32; ++i) { ar[i] = nr[REV5[i]]; ai[i] = ni[REV5[i]]; }
    fft32<+1>(ar, ai);
    // thread owns column x=line; ar[y] -> A-side channel, ai[y] -> B-side
    const float wx = wrow;
    // A side: T<4 -> ch0 of patch A; T>=4 -> ch2 of patch A
    {
      const int ox = pxA * 8 - 32 + line;
      if ((unsigned)ox < 512u) {
        const int cA = (T < 4) ? 0 : 2;
        float* dA;
        if (MODE == 1) {
          const int par = ((pyA & 3) << 2) | (pxA & 3);
          dA = dst + (size_t)par * PLANE_FLOATS + ((size_t)bA * 3 + cA) * 262144 + ox;
        } else {
          dA = dst + ((size_t)bA * 3 + cA) * 262144 + ox;
        }
        const int oy0 = pyA * 8 - 32;
        #pragma unroll
        for (int y = 0; y < 32; ++y) {
          const int oy = oy0 + y;
          if ((unsigned)oy < 512u) {
            const float wv = wx * W1C[y];
            const float val = (ar[y] * INV6144 + mA * wv) * wv;
            if (MODE == 1) dA[(size_t)oy * 512] = val;
            else           atomicAdd(&dA[(size_t)oy * 512], val);
          }
        }
      }
    }
    // B side: T<4 -> ch1 of patch A; T>=4 -> ch2 of patch B
    {
      const int ox = pxB * 8 - 32 + line;
      if ((unsigned)ox < 512u) {
        const int cB = (T < 4) ? 1 : 2;
        float* dB;
        if (MODE == 1) {
          const int par = ((pyB & 3) << 2) | (pxB & 3);
          dB = dst + (size_t)par * PLANE_FLOATS + ((size_t)bB * 3 + cB) * 262144 + ox;
        } else {
          dB = dst + ((size_t)bB * 3 + cB) * 262144 + ox;
        }
        const int oy0 = pyB * 8 - 32;
        #pragma unroll
        for (int y = 0; y < 32; ++y) {
          const int oy = oy0 + y;
          if ((unsigned)oy < 512u) {
            const float wv = wx * W1C[y];
            const float val = (ai[y] * INV6144 + mB * wv) * wv;
            if (MODE == 1) dB[(size_t)oy * 512] = val;
            else           atomicAdd(&dB[(size_t)oy * 512], val);
          }
        }
      }
    }
  }
}

// mask(y,x) = mrow(y%8) * mrow(x%8), mrow(r) = sum_k w1[r+8k]^2
__device__ __forceinline__ float mask_row(int r) {
  float m = 0.f;
  #pragma unroll
  for (int k = 0; k < 4; ++k) {
    float tt = (float)(r + 8 * k) - 15.5f;
    float w = __expf(tt * tt * INV_WIN_DEN);
    m += w * w;
  }
  return m;
}

// MODE1 phase 2: out = (sum of 16 planes + eps) / (mask + eps)
__global__ void wiener_combine(const float* __restrict__ ws, float* __restrict__ out)
{
  const int i = blockIdx.x * 256 + threadIdx.x;   // out_size = 3,145,728
  const int xx = i & 511;
  const int yy = (i >> 9) & 511;
  float s = 0.f;
  #pragma unroll
  for (int p = 0; p < 16; ++p) s += ws[(size_t)p * PLANE_FLOATS + i];
  out[i] = (s + EPSF) / (mask_row(yy & 7) * mask_row(xx & 7) + EPSF);
}

// MODE0 phase 2: in-place normalize after atomic accumulation
__global__ void wiener_norm(float* __restrict__ out)
{
  const int i = blockIdx.x * 256 + threadIdx.x;
  const int xx = i & 511;
  const int yy = (i >> 9) & 511;
  out[i] = (out[i] + EPSF) / (mask_row(yy & 7) * mask_row(xx & 7) + EPSF);
}

extern "C" void kernel_launch(void* const* d_in, const int* in_sizes, int n_in,
                              void* d_out, int out_size, void* d_ws, size_t ws_size,
                              hipStream_t stream)
{
  const float* I = (const float*)d_in[0];
  const float* S = (const float*)d_in[1];
  float* out = (float*)d_out;
  const int nblocks = (4 * 67 * 67) / 4;   // 4 patches per block, 4489 blocks

  if (ws_size >= WS_NEEDED && d_ws != nullptr) {
    float* ws = (float*)d_ws;
    // every in-crop plane pixel is written exactly once -> no zeroing needed
    wiener_patch<1><<<dim3(nblocks), dim3(256), 0, stream>>>(I, S, ws);
    wiener_combine<<<dim3(out_size / 256), dim3(256), 0, stream>>>(ws, out);
  } else {
    hipMemsetAsync(out, 0, (size_t)out_size * sizeof(float), stream);
    wiener_patch<0><<<dim3(nblocks), dim3(256), 0, stream>>>(I, S, out);
    wiener_norm<<<dim3(out_size / 256), dim3(256), 0, stream>>>(out);
  }
}

// Round 7
// 230.169 us; speedup vs baseline: 1.8972x; 1.8972x over previous
//
#include <hip/hip_runtime.h>
#include <hip/hip_fp16.h>

// ---------------------------------------------------------------------------
// Wiener 3D patch filter, MI355X — channel-packed FFT, fp16-packed-complex LDS.
// Structure = round-5 (verified): 4 patches / 256-thread block, 6 complex
// planes, separate barrier phases. Single change: each complex LDS value is
// one __half2 (re,im) -> LDS 51KB -> 25.6KB (5-6 blocks/CU) and DS ops halve.
//   plane p (p=0..3): Z_p = fft2(a0_p + i*a1_p)   (later reused for Q_p)
//   plane 4+j (j=0,1): W_j = fft2(a2_{2j} + i*a2_{2j+1})  (reused for R_j)
// Overlap-add via 16 parity planes in d_ws (no atomics); atomic fallback.
// ---------------------------------------------------------------------------

constexpr float TWR[16] = {
  1.0f, 0.98078528040323044f, 0.92387953251128674f, 0.83146961230254524f,
  0.70710678118654752f, 0.55557023301960222f, 0.38268343236508977f, 0.19509032201612827f,
  0.0f, -0.19509032201612827f, -0.38268343236508977f, -0.55557023301960222f,
  -0.70710678118654752f, -0.83146961230254524f, -0.92387953251128674f, -0.98078528040323044f
};
constexpr float TWI[16] = {
  -0.0f, -0.19509032201612827f, -0.38268343236508977f, -0.55557023301960222f,
  -0.70710678118654752f, -0.83146961230254524f, -0.92387953251128674f, -0.98078528040323044f,
  -1.0f, -0.98078528040323044f, -0.92387953251128674f, -0.83146961230254524f,
  -0.70710678118654752f, -0.55557023301960222f, -0.38268343236508977f, -0.19509032201612827f
};
constexpr int REV5[32] = {0,16,8,24,4,20,12,28,2,18,10,26,6,22,14,30,
                          1,17,9,25,5,21,13,29,3,19,11,27,7,23,15,31};
// W1C[i] = exp(-(i-15.5)^2 / 76.8)   [verified in round 6]
constexpr float W1C[32] = {
  0.0437942f, 0.0647235f, 0.0931963f, 0.1307451f,
  0.1787074f, 0.2379852f, 0.3087788f, 0.3903331f,
  0.4807436f, 0.5768747f, 0.6744349f, 0.7682257f,
  0.8525655f, 0.9218431f, 0.9711281f, 0.9967501f,
  0.9967501f, 0.9711281f, 0.9218431f, 0.8525655f,
  0.7682257f, 0.6744349f, 0.5768747f, 0.4807436f,
  0.3903331f, 0.3087788f, 0.2379852f, 0.1787074f,
  0.1307451f, 0.0931963f, 0.0647235f, 0.0437942f
};

constexpr float S3    = 0.86602540378443865f;  // sqrt(3)/2
constexpr float EPSF  = 1e-15f;
constexpr float INV_WIN_DEN = -1.0f / 76.8f;
constexpr float CS    = 1.1499041e-4f;         // (mean win^2)^2 / 1024 [verified r6]
constexpr float INV6144 = 1.0f / 6144.0f;

#define PLANE_FLOATS (4 * 3 * 512 * 512)
#define WS_NEEDED    ((size_t)16 * PLANE_FLOATS * 4)
#define LSTR 33                 // row stride in half2 (= dwords), padded
#define PL   (32 * LSTR)        // complex plane = 1056 half2

// ---- butterfly with compile-time twiddle specialization ----
template<int SIGN, int K>
__device__ __forceinline__ void bfly(float& ur, float& ui, float& vr, float& vi) {
  if constexpr (K == 0) {
    float tr = vr, ti = vi;
    vr = ur - tr; vi = ui - ti; ur += tr; ui += ti;
  } else if constexpr (K == 8) {
    float tr = (SIGN < 0) ?  vi : -vi;
    float ti = (SIGN < 0) ? -vr :  vr;
    vr = ur - tr; vi = ui - ti; ur += tr; ui += ti;
  } else {
    constexpr float wr = TWR[K];
    constexpr float wi = (SIGN < 0) ? TWI[K] : -TWI[K];
    float tr = wr * vr - wi * vi;
    float ti = wr * vi + wi * vr;
    vr = ur - tr; vi = ui - ti; ur += tr; ui += ti;
  }
}

template<int SIGN, int S, int J>
__device__ __forceinline__ void stage_j(float* ar, float* ai) {
  constexpr int m = 1 << S, h = m >> 1, ts = 32 >> S;
  if constexpr (J < h) {
    #pragma unroll
    for (int k = 0; k < 32; k += m)
      bfly<SIGN, J * ts>(ar[k + J], ai[k + J], ar[k + J + h], ai[k + J + h]);
    stage_j<SIGN, S, J + 1>(ar, ai);
  }
}

template<int SIGN>
__device__ __forceinline__ void fft32(float* ar, float* ai) {
  stage_j<SIGN, 1, 0>(ar, ai);
  stage_j<SIGN, 2, 0>(ar, ai);
  stage_j<SIGN, 3, 0>(ar, ai);
  stage_j<SIGN, 4, 0>(ar, ai);
  stage_j<SIGN, 5, 0>(ar, ai);
}

// reflect-pad index mapping, N=512, mode='reflect'
__device__ __forceinline__ int refl(int v) {
  v = (v < 0) ? -v : v;
  return (v >= 512) ? (1022 - v) : v;
}

// MODE 0: atomicAdd into out (fallback).  MODE 1: plain store into parity plane.
template<int MODE>
__global__ __launch_bounds__(256)
void wiener_patch(const float* __restrict__ I,
                  const float* __restrict__ Sd,
                  float* __restrict__ dst)
{
  __shared__ __half2 sc[6 * PL];   // 25,344 B
  __shared__ float w1[32];
  __shared__ float red[24];        // [p*6 + {I0,I1,I2,S0,S1,S2}]
  __shared__ int   pgeo[16];       // [p*4 + {py,px,b,parity}]

  const int t  = threadIdx.x;
  const int q  = t >> 6;           // patch slot 0..3 (wave == patch)
  const int tl = t & 63;

  if (t < 32) { float tt = (float)t - 15.5f; w1[t] = __expf(tt * tt * INV_WIN_DEN); }
  if (t < 4) {
    int pp = blockIdx.x * 4 + t;
    int ppx = pp % 67 + 1;  pp /= 67;
    int ppy = pp % 67 + 1;
    int pb  = pp / 67;
    pgeo[t*4+0] = ppy; pgeo[t*4+1] = ppx; pgeo[t*4+2] = pb;
    pgeo[t*4+3] = ((ppy & 3) << 2) | (ppx & 3);
  }
  __syncthreads();

  // ---- load: 64 threads/patch; (a0,a1) -> half2 Z plane, a2 -> b16 W half --
  const int py = pgeo[q*4+0], px = pgeo[q*4+1], b = pgeo[q*4+2];
  {
    float sI0=0.f,sI1=0.f,sI2=0.f,sS0=0.f,sS1=0.f,sS2=0.f;
    const int gy0 = py * 8 - 32, gx0 = px * 8 - 32;
    const int x  = tl & 31;
    const int y0 = tl >> 5;        // 0/1; rows y0+2i
    const int rx = refl(gx0 + x);
    const size_t bbase = (size_t)b * 3 * 262144;
    const int zb = q * PL;
    const int wb = (4 + (q >> 1)) * PL;
    const int par = q & 1;
    __half* scH = reinterpret_cast<__half*>(sc);
    #pragma unroll
    for (int i = 0; i < 16; ++i) {
      int y  = y0 + 2 * i;
      int ry = refl(gy0 + y);
      size_t g = bbase + (size_t)ry * 512 + rx;
      float v0 = I[g];            float u0 = Sd[g];
      float v1 = I[g + 262144];   float u1 = Sd[g + 262144];
      float v2 = I[g + 524288];   float u2 = Sd[g + 524288];
      sI0 += v0; sI1 += v1; sI2 += v2;
      sS0 += u0; sS1 += u1; sS2 += u2;
      const int l = y * LSTR + x;
      sc[zb + l] = __floats2half2_rn(v0, v1);
      scH[2 * (wb + l) + par] = __float2half_rn(v2);
    }
    #pragma unroll
    for (int off = 32; off > 0; off >>= 1) {
      sI0 += __shfl_down(sI0, off); sI1 += __shfl_down(sI1, off); sI2 += __shfl_down(sI2, off);
      sS0 += __shfl_down(sS0, off); sS1 += __shfl_down(sS1, off); sS2 += __shfl_down(sS2, off);
    }
    if (tl == 0) {                 // wave == patch: direct write, no atomics
      red[q*6+0] = sI0; red[q*6+1] = sI1; red[q*6+2] = sI2;
      red[q*6+3] = sS0; red[q*6+4] = sS1; red[q*6+5] = sS2;
    }
  }
  __syncthreads();

  // ---- pass 1: fwd row FFTs (window x0.5 + mean-subtract fused) -----------
  if (t < 192) {
    const int T = t >> 5, row = t & 31;
    float ma, mb;
    if (T < 4) { ma = red[T*6+0] * (1.f/1024.f); mb = red[T*6+1] * (1.f/1024.f); }
    else { const int j = T - 4; ma = red[(2*j)*6+2] * (1.f/1024.f); mb = red[(2*j+1)*6+2] * (1.f/1024.f); }
    const int rb = T * PL + row * LSTR;
    const float ty = (float)row - 15.5f;
    const float hw = 0.5f * __expf(ty * ty * INV_WIN_DEN);
    float ar[32], ai[32];
    #pragma unroll
    for (int i = 0; i < 32; ++i) {
      const int s = REV5[i];
      const __half2 z = sc[rb + s];
      const float wv = hw * W1C[s];
      ar[i] = (__low2float(z)  - ma) * wv;
      ai[i] = (__high2float(z) - mb) * wv;
    }
    fft32<-1>(ar, ai);
    #pragma unroll
    for (int i = 0; i < 32; ++i) sc[rb + i] = __floats2half2_rn(ar[i], ai[i]);
  }
  __syncthreads();

  // ---- pass 2: fwd col FFTs ------------------------------------------------
  if (t < 192) {
    const int T = t >> 5, col = t & 31;
    const int cb = T * PL + col;
    float ar[32], ai[32];
    #pragma unroll
    for (int i = 0; i < 32; ++i) {
      const __half2 z = sc[cb + LSTR * REV5[i]];
      ar[i] = __low2float(z); ai[i] = __high2float(z);
    }
    fft32<-1>(ar, ai);
    #pragma unroll
    for (int i = 0; i < 32; ++i) sc[cb + LSTR * i] = __floats2half2_rn(ar[i], ai[i]);
  }
  __syncthreads();

  // ---- spectral middle: mirror pairs (k, -k), bank-aware ky-walk ----------
  for (int task = t; task < 1028; task += 256) {
    const int j = (task >= 514) ? 1 : 0;
    const int u = task - j * 514;
    int ky, kx;
    if (u < 480) { ky = u & 31; kx = 1 + (u >> 5); }
    else { const int e = u - 480; kx = (e >= 17) ? 16 : 0; ky = (e >= 17) ? (e - 17) : e; }
    const int my = (32 - ky) & 31, mx = (32 - kx) & 31;
    const int ok = ky * LSTR + kx, om = my * LSTR + mx;
    const int zp0 = (2 * j) * PL, zp1 = zp0 + PL, wp = (4 + j) * PL;
    const __half2 Wkh = sc[wp + ok], Wmh = sc[wp + om];
    const float Wkr = __low2float(Wkh), Wki = __high2float(Wkh);
    const float Wmr = __low2float(Wmh), Wmi = __high2float(Wmh);
    float B2r[2], B2i[2];
    #pragma unroll
    for (int lp = 0; lp < 2; ++lp) {
      const int zp = lp ? zp1 : zp0;
      const __half2 Zkh = sc[zp + ok], Zmh = sc[zp + om];
      const float Zkr = __low2float(Zkh), Zki = __high2float(Zkh);
      const float Zmr = __low2float(Zmh), Zmi = __high2float(Zmh);
      // Hermitian splits (x2 true scale; 0.5 folded into forward window)
      const float F0r = Zkr + Zmr, F0i = Zki - Zmi;
      const float F1r = Zki + Zmi, F1i = Zmr - Zkr;
      const float F2r = lp ? (Wki + Wmi) : (Wkr + Wmr);
      const float F2i = lp ? (Wmr - Wkr) : (Wki - Wmi);
      // forward channel DFT
      const float Spr = F1r + F2r, Spi = F1i + F2i, Smr = F1r - F2r, Smi = F1i - F2i;
      const float A0r = F0r + Spr,        A0i = F0i + Spi;
      const float t1r = F0r - 0.5f * Spr, t1i = F0i - 0.5f * Spi;
      const float A1r = t1r + S3 * Smi,   A1i = t1i - S3 * Smr;
      const float A2r = t1r - S3 * Smi,   A2i = t1i + S3 * Smr;
      const float P0 = A0r * A0r + A0i * A0i + EPSF;
      const float P1 = A1r * A1r + A1i * A1i + EPSF;
      const float P2 = A2r * A2r + A2i * A2i + EPSF;
      const int p = 2 * j + lp;
      const float s0 = red[p*6+3], s1 = red[p*6+4], s2v = red[p*6+5];
      const float Pv0 = CS * s0 * s0, Pv1 = CS * s1 * s1, Pv2 = CS * s2v * s2v;
      const float rp0 = __builtin_amdgcn_rcpf(P0);
      const float rp1 = __builtin_amdgcn_rcpf(P1);
      const float rp2 = __builtin_amdgcn_rcpf(P2);
      const float H0  = fmaxf(P0 - Pv0, 0.f) * rp0;
      const float H1k = fmaxf(P1 - Pv1, 0.f) * rp1;
      const float H2k = fmaxf(P2 - Pv2, 0.f) * rp2;
      const float H1m = fmaxf(P2 - Pv1, 0.f) * rp2;   // mirror: P1(m)=P2(k)
      const float H2m = fmaxf(P1 - Pv2, 0.f) * rp1;   // mirror: P2(m)=P1(k)
      // k side: gain + inverse channel DFT
      float G0r = H0 * A0r,  G0i = H0 * A0i;
      float G1r = H1k * A1r, G1i = H1k * A1i;
      float G2r = H2k * A2r, G2i = H2k * A2i;
      float Qpr = G1r + G2r, Qpi = G1i + G2i, Qmr = G1r - G2r, Qmi = G1i - G2i;
      const float M0kr = G0r + Qpr,        M0ki = G0i + Qpi;
      float u1r = G0r - 0.5f * Qpr,        u1i = G0i - 0.5f * Qpi;
      const float M1kr = u1r - S3 * Qmi,   M1ki = u1i + S3 * Qmr;
      const float M2kr = u1r + S3 * Qmi,   M2ki = u1i - S3 * Qmr;
      // m side: A0->conj(A0), A1->conj(A2), A2->conj(A1)
      G0r = H0 * A0r;   G0i = -H0 * A0i;
      G1r = H1m * A2r;  G1i = -H1m * A2i;
      G2r = H2m * A1r;  G2i = -H2m * A1i;
      Qpr = G1r + G2r;  Qpi = G1i + G2i;  Qmr = G1r - G2r;  Qmi = G1i - G2i;
      const float M0mr = G0r + Qpr,        M0mi = G0i + Qpi;
      u1r = G0r - 0.5f * Qpr;              u1i = G0i - 0.5f * Qpi;
      const float M1mr = u1r - S3 * Qmi,   M1mi = u1i + S3 * Qmr;
      const float M2mr = u1r + S3 * Qmi,   M2mi = u1i - S3 * Qmr;
      // Hermitian parts x2 (1/2 folded into epilogue 1/6144)
      const float B0r = M0kr + M0mr, B0i = M0ki - M0mi;
      const float B1r = M1kr + M1mr, B1i = M1ki - M1mi;
      B2r[lp] = M2kr + M2mr;  B2i[lp] = M2ki - M2mi;
      // pack Q = H0 + i*H1 over Z plane (task owns both k and m)
      sc[zp + ok] = __floats2half2_rn(B0r - B1i, B0i + B1r);
      sc[zp + om] = __floats2half2_rn(B0r + B1i, B1r - B0i);
    }
    // pack R = H2_{p0} + i*H2_{p1} over W plane
    sc[wp + ok] = __floats2half2_rn(B2r[0] - B2i[1], B2i[0] + B2r[1]);
    sc[wp + om] = __floats2half2_rn(B2r[0] + B2i[1], B2r[1] - B2i[0]);
  }
  __syncthreads();

  // ---- pass 3: inv col FFTs ------------------------------------------------
  if (t < 192) {
    const int T = t >> 5, col = t & 31;
    const int cb = T * PL + col;
    float ar[32], ai[32];
    #pragma unroll
    for (int i = 0; i < 32; ++i) {
      const __half2 z = sc[cb + LSTR * REV5[i]];
      ar[i] = __low2float(z); ai[i] = __high2float(z);
    }
    fft32<+1>(ar, ai);
    #pragma unroll
    for (int i = 0; i < 32; ++i) sc[cb + LSTR * i] = __floats2half2_rn(ar[i], ai[i]);
  }
  __syncthreads();

  // ---- pass 4: inv row FFTs ------------------------------------------------
  if (t < 192) {
    const int T = t >> 5, row = t & 31;
    const int rb = T * PL + row * LSTR;
    float ar[32], ai[32];
    #pragma unroll
    for (int i = 0; i < 32; ++i) {
      const __half2 z = sc[rb + REV5[i]];
      ar[i] = __low2float(z); ai[i] = __high2float(z);
    }
    fft32<+1>(ar, ai);
    #pragma unroll
    for (int i = 0; i < 32; ++i) sc[rb + i] = __floats2half2_rn(ar[i], ai[i]);
  }
  __syncthreads();

  // ---- epilogue: ch0=Re(Q), ch1=Im(Q), ch2=Re/Im(R); window + mean --------
  for (int jj = t; jj < 12288; jj += 256) {
    const int x2 = jj & 31, y2 = (jj >> 5) & 31;
    const int rest = jj >> 10;          // 0..11, wave-uniform
    const int p = rest & 3, c = rest >> 2;
    const int ppy = pgeo[p*4+0], ppx = pgeo[p*4+1], pb = pgeo[p*4+2];
    const int oy = ppy * 8 + y2 - 32, ox = ppx * 8 + x2 - 32;
    if (oy >= 0 && oy < 512 && ox >= 0 && ox < 512) {
      const int l = y2 * LSTR + x2;
      __half2 z;
      bool lo;
      if (c == 2) { z = sc[(4 + (p >> 1)) * PL + l]; lo = ((p & 1) == 0); }
      else        { z = sc[p * PL + l];              lo = (c == 0); }
      const float v = lo ? __low2float(z) : __high2float(z);
      const float wv = w1[y2] * w1[x2];               // win == win_interp
      const float mc = red[p*6 + c] * (1.f/1024.f);
      const float val = (v * INV6144 + mc * wv) * wv;
      const size_t off = (((size_t)pb * 3 + c) * 512 + oy) * 512 + ox;
      if (MODE == 1) dst[(size_t)pgeo[p*4+3] * PLANE_FLOATS + off] = val;
      else           atomicAdd(dst + off, val);
    }
  }
}

// mask(y,x) = mrow(y%8) * mrow(x%8), mrow(r) = sum_k w1[r+8k]^2
__device__ __forceinline__ float mask_row(int r) {
  float m = 0.f;
  #pragma unroll
  for (int k = 0; k < 4; ++k) {
    float tt = (float)(r + 8 * k) - 15.5f;
    float w = __expf(tt * tt * INV_WIN_DEN);
    m += w * w;
  }
  return m;
}

// MODE1 phase 2: out = (sum of 16 planes + eps) / (mask + eps)
__global__ void wiener_combine(const float* __restrict__ ws, float* __restrict__ out)
{
  const int i = blockIdx.x * 256 + threadIdx.x;   // out_size = 3,145,728
  const int xx = i & 511;
  const int yy = (i >> 9) & 511;
  float s = 0.f;
  #pragma unroll
  for (int p = 0; p < 16; ++p) s += ws[(size_t)p * PLANE_FLOATS + i];
  out[i] = (s + EPSF) / (mask_row(yy & 7) * mask_row(xx & 7) + EPSF);
}

// MODE0 phase 2: in-place normalize after atomic accumulation
__global__ void wiener_norm(float* __restrict__ out)
{
  const int i = blockIdx.x * 256 + threadIdx.x;
  const int xx = i & 511;
  const int yy = (i >> 9) & 511;
  out[i] = (out[i] + EPSF) / (mask_row(yy & 7) * mask_row(xx & 7) + EPSF);
}

extern "C" void kernel_launch(void* const* d_in, const int* in_sizes, int n_in,
                              void* d_out, int out_size, void* d_ws, size_t ws_size,
                              hipStream_t stream)
{
  const float* I = (const float*)d_in[0];
  const float* S = (const float*)d_in[1];
  float* out = (float*)d_out;
  const int nblocks = (4 * 67 * 67) / 4;   // 4 patches per block, 4489 blocks

  if (ws_size >= WS_NEEDED && d_ws != nullptr) {
    float* ws = (float*)d_ws;
    // every in-crop plane pixel is written exactly once -> no zeroing needed
    wiener_patch<1><<<dim3(nblocks), dim3(256), 0, stream>>>(I, S, ws);
    wiener_combine<<<dim3(out_size / 256), dim3(256), 0, stream>>>(ws, out);
  } else {
    hipMemsetAsync(out, 0, (size_t)out_size * sizeof(float), stream);
    wiener_patch<0><<<dim3(nblocks), dim3(256), 0, stream>>>(I, S, out);
    wiener_norm<<<dim3(out_size / 256), dim3(256), 0, stream>>>(out);
  }
}

// Round 8
// 167.296 us; speedup vs baseline: 2.6102x; 1.3758x over previous
//
#include <hip/hip_runtime.h>
#include <hip/hip_fp16.h>

// ---------------------------------------------------------------------------
// Wiener 3D patch filter, MI355X — channel-packed FFT, fp16-packed-complex LDS,
// direct register->global epilogue.
// 4 patches / 256-thread block; 6 complex planes (half2, row stride 33):
//   plane p (p=0..3): Z_p = fft2(a0_p + i*a1_p)   (later reused for Q_p)
//   plane 4+j (j=0,1): W_j = fft2(a2_{2j} + i*a2_{2j+1})  (reused for R_j)
// Inverse passes ordered row-then-col so the last pass owns spatial columns
// and stores straight from registers (no epilogue phase, one less barrier).
// Overlap-add via 16 parity planes in d_ws (no atomics); atomic fallback.
// ---------------------------------------------------------------------------

constexpr float TWR[16] = {
  1.0f, 0.98078528040323044f, 0.92387953251128674f, 0.83146961230254524f,
  0.70710678118654752f, 0.55557023301960222f, 0.38268343236508977f, 0.19509032201612827f,
  0.0f, -0.19509032201612827f, -0.38268343236508977f, -0.55557023301960222f,
  -0.70710678118654752f, -0.83146961230254524f, -0.92387953251128674f, -0.98078528040323044f
};
constexpr float TWI[16] = {
  -0.0f, -0.19509032201612827f, -0.38268343236508977f, -0.55557023301960222f,
  -0.70710678118654752f, -0.83146961230254524f, -0.92387953251128674f, -0.98078528040323044f,
  -1.0f, -0.98078528040323044f, -0.92387953251128674f, -0.83146961230254524f,
  -0.70710678118654752f, -0.55557023301960222f, -0.38268343236508977f, -0.19509032201612827f
};
constexpr int REV5[32] = {0,16,8,24,4,20,12,28,2,18,10,26,6,22,14,30,
                          1,17,9,25,5,21,13,29,3,19,11,27,7,23,15,31};
// W1C[i] = exp(-(i-15.5)^2 / 76.8)
constexpr float W1C[32] = {
  0.0437942f, 0.0647235f, 0.0931963f, 0.1307451f,
  0.1787074f, 0.2379852f, 0.3087788f, 0.3903331f,
  0.4807436f, 0.5768747f, 0.6744349f, 0.7682257f,
  0.8525655f, 0.9218431f, 0.9711281f, 0.9967501f,
  0.9967501f, 0.9711281f, 0.9218431f, 0.8525655f,
  0.7682257f, 0.6744349f, 0.5768747f, 0.4807436f,
  0.3903331f, 0.3087788f, 0.2379852f, 0.1787074f,
  0.1307451f, 0.0931963f, 0.0647235f, 0.0437942f
};

constexpr float S3    = 0.86602540378443865f;  // sqrt(3)/2
constexpr float EPSF  = 1e-15f;
constexpr float INV_WIN_DEN = -1.0f / 76.8f;
constexpr float CS    = 1.1499041e-4f;         // (mean win^2)^2 / 1024
constexpr float INV6144 = 1.0f / 6144.0f;

#define PLANE_FLOATS (4 * 3 * 512 * 512)
#define WS_NEEDED    ((size_t)16 * PLANE_FLOATS * 4)
#define LSTR 33                 // row stride in half2 (= dwords), padded
#define PL   (32 * LSTR)        // complex plane = 1056 half2

// ---- butterfly with compile-time twiddle specialization ----
template<int SIGN, int K>
__device__ __forceinline__ void bfly(float& ur, float& ui, float& vr, float& vi) {
  if constexpr (K == 0) {
    float tr = vr, ti = vi;
    vr = ur - tr; vi = ui - ti; ur += tr; ui += ti;
  } else if constexpr (K == 8) {
    float tr = (SIGN < 0) ?  vi : -vi;
    float ti = (SIGN < 0) ? -vr :  vr;
    vr = ur - tr; vi = ui - ti; ur += tr; ui += ti;
  } else {
    constexpr float wr = TWR[K];
    constexpr float wi = (SIGN < 0) ? TWI[K] : -TWI[K];
    float tr = wr * vr - wi * vi;
    float ti = wr * vi + wi * vr;
    vr = ur - tr; vi = ui - ti; ur += tr; ui += ti;
  }
}

template<int SIGN, int S, int J>
__device__ __forceinline__ void stage_j(float* ar, float* ai) {
  constexpr int m = 1 << S, h = m >> 1, ts = 32 >> S;
  if constexpr (J < h) {
    #pragma unroll
    for (int k = 0; k < 32; k += m)
      bfly<SIGN, J * ts>(ar[k + J], ai[k + J], ar[k + J + h], ai[k + J + h]);
    stage_j<SIGN, S, J + 1>(ar, ai);
  }
}

template<int SIGN>
__device__ __forceinline__ void fft32(float* ar, float* ai) {
  stage_j<SIGN, 1, 0>(ar, ai);
  stage_j<SIGN, 2, 0>(ar, ai);
  stage_j<SIGN, 3, 0>(ar, ai);
  stage_j<SIGN, 4, 0>(ar, ai);
  stage_j<SIGN, 5, 0>(ar, ai);
}

// reflect-pad index mapping, N=512, mode='reflect'
__device__ __forceinline__ int refl(int v) {
  v = (v < 0) ? -v : v;
  return (v >= 512) ? (1022 - v) : v;
}

// MODE 0: atomicAdd into out (fallback).  MODE 1: plain store into parity plane.
template<int MODE>
__global__ __launch_bounds__(256)
void wiener_patch(const float* __restrict__ I,
                  const float* __restrict__ Sd,
                  float* __restrict__ dst)
{
  __shared__ __half2 sc[6 * PL];   // 25,344 B
  __shared__ float red[24];        // [p*6 + {I0,I1,I2,S0,S1,S2}]
  __shared__ int   pgeo[16];       // [p*4 + {py,px,b,parity}]

  const int t  = threadIdx.x;
  const int q  = t >> 6;           // patch slot 0..3 (wave == patch)
  const int tl = t & 63;

  if (t < 4) {
    int pp = blockIdx.x * 4 + t;
    int ppx = pp % 67 + 1;  pp /= 67;
    int ppy = pp % 67 + 1;
    int pb  = pp / 67;
    pgeo[t*4+0] = ppy; pgeo[t*4+1] = ppx; pgeo[t*4+2] = pb;
    pgeo[t*4+3] = ((ppy & 3) << 2) | (ppx & 3);
  }
  __syncthreads();

  // ---- load: 64 threads/patch; (a0,a1) -> half2 Z plane, a2 -> b16 W half --
  const int py = pgeo[q*4+0], px = pgeo[q*4+1], b = pgeo[q*4+2];
  {
    float sI0=0.f,sI1=0.f,sI2=0.f,sS0=0.f,sS1=0.f,sS2=0.f;
    const int gy0 = py * 8 - 32, gx0 = px * 8 - 32;
    const int x  = tl & 31;
    const int y0 = tl >> 5;        // 0/1; rows y0+2i
    const int rx = refl(gx0 + x);
    const size_t bbase = (size_t)b * 3 * 262144;
    const int zb = q * PL;
    const int wb = (4 + (q >> 1)) * PL;
    const int par = q & 1;
    __half* scH = reinterpret_cast<__half*>(sc);
    #pragma unroll
    for (int i = 0; i < 16; ++i) {
      int y  = y0 + 2 * i;
      int ry = refl(gy0 + y);
      size_t g = bbase + (size_t)ry * 512 + rx;
      float v0 = I[g];            float u0 = Sd[g];
      float v1 = I[g + 262144];   float u1 = Sd[g + 262144];
      float v2 = I[g + 524288];   float u2 = Sd[g + 524288];
      sI0 += v0; sI1 += v1; sI2 += v2;
      sS0 += u0; sS1 += u1; sS2 += u2;
      const int l = y * LSTR + x;
      sc[zb + l] = __floats2half2_rn(v0, v1);
      scH[2 * (wb + l) + par] = __float2half_rn(v2);
    }
    #pragma unroll
    for (int off = 32; off > 0; off >>= 1) {
      sI0 += __shfl_down(sI0, off); sI1 += __shfl_down(sI1, off); sI2 += __shfl_down(sI2, off);
      sS0 += __shfl_down(sS0, off); sS1 += __shfl_down(sS1, off); sS2 += __shfl_down(sS2, off);
    }
    if (tl == 0) {                 // wave == patch: direct write, no atomics
      red[q*6+0] = sI0; red[q*6+1] = sI1; red[q*6+2] = sI2;
      red[q*6+3] = sS0; red[q*6+4] = sS1; red[q*6+5] = sS2;
    }
  }
  __syncthreads();

  // ---- pass 1: fwd row FFTs (window x0.5 + mean-subtract fused) -----------
  if (t < 192) {
    const int T = t >> 5, row = t & 31;
    float ma, mb;
    if (T < 4) { ma = red[T*6+0] * (1.f/1024.f); mb = red[T*6+1] * (1.f/1024.f); }
    else { const int j = T - 4; ma = red[(2*j)*6+2] * (1.f/1024.f); mb = red[(2*j+1)*6+2] * (1.f/1024.f); }
    const int rb = T * PL + row * LSTR;
    const float ty = (float)row - 15.5f;
    const float hw = 0.5f * __expf(ty * ty * INV_WIN_DEN);
    float ar[32], ai[32];
    #pragma unroll
    for (int i = 0; i < 32; ++i) {
      const int s = REV5[i];
      const __half2 z = sc[rb + s];
      const float wv = hw * W1C[s];
      ar[i] = (__low2float(z)  - ma) * wv;
      ai[i] = (__high2float(z) - mb) * wv;
    }
    fft32<-1>(ar, ai);
    #pragma unroll
    for (int i = 0; i < 32; ++i) sc[rb + i] = __floats2half2_rn(ar[i], ai[i]);
  }
  __syncthreads();

  // ---- pass 2: fwd col FFTs ------------------------------------------------
  if (t < 192) {
    const int T = t >> 5, col = t & 31;
    const int cb = T * PL + col;
    float ar[32], ai[32];
    #pragma unroll
    for (int i = 0; i < 32; ++i) {
      const __half2 z = sc[cb + LSTR * REV5[i]];
      ar[i] = __low2float(z); ai[i] = __high2float(z);
    }
    fft32<-1>(ar, ai);
    #pragma unroll
    for (int i = 0; i < 32; ++i) sc[cb + LSTR * i] = __floats2half2_rn(ar[i], ai[i]);
  }
  __syncthreads();

  // ---- spectral middle: mirror pairs (k, -k), bank-aware ky-walk ----------
  for (int task = t; task < 1028; task += 256) {
    const int j = (task >= 514) ? 1 : 0;
    const int u = task - j * 514;
    int ky, kx;
    if (u < 480) { ky = u & 31; kx = 1 + (u >> 5); }
    else { const int e = u - 480; kx = (e >= 17) ? 16 : 0; ky = (e >= 17) ? (e - 17) : e; }
    const int my = (32 - ky) & 31, mx = (32 - kx) & 31;
    const int ok = ky * LSTR + kx, om = my * LSTR + mx;
    const int zp0 = (2 * j) * PL, zp1 = zp0 + PL, wp = (4 + j) * PL;
    const __half2 Wkh = sc[wp + ok], Wmh = sc[wp + om];
    const float Wkr = __low2float(Wkh), Wki = __high2float(Wkh);
    const float Wmr = __low2float(Wmh), Wmi = __high2float(Wmh);
    float B2r[2], B2i[2];
    #pragma unroll
    for (int lp = 0; lp < 2; ++lp) {
      const int zp = lp ? zp1 : zp0;
      const __half2 Zkh = sc[zp + ok], Zmh = sc[zp + om];
      const float Zkr = __low2float(Zkh), Zki = __high2float(Zkh);
      const float Zmr = __low2float(Zmh), Zmi = __high2float(Zmh);
      // Hermitian splits (x2 true scale; 0.5 folded into forward window)
      const float F0r = Zkr + Zmr, F0i = Zki - Zmi;
      const float F1r = Zki + Zmi, F1i = Zmr - Zkr;
      const float F2r = lp ? (Wki + Wmi) : (Wkr + Wmr);
      const float F2i = lp ? (Wmr - Wkr) : (Wki - Wmi);
      // forward channel DFT
      const float Spr = F1r + F2r, Spi = F1i + F2i, Smr = F1r - F2r, Smi = F1i - F2i;
      const float A0r = F0r + Spr,        A0i = F0i + Spi;
      const float t1r = F0r - 0.5f * Spr, t1i = F0i - 0.5f * Spi;
      const float A1r = t1r + S3 * Smi,   A1i = t1i - S3 * Smr;
      const float A2r = t1r - S3 * Smi,   A2i = t1i + S3 * Smr;
      const float P0 = A0r * A0r + A0i * A0i + EPSF;
      const float P1 = A1r * A1r + A1i * A1i + EPSF;
      const float P2 = A2r * A2r + A2i * A2i + EPSF;
      const int p = 2 * j + lp;
      const float s0 = red[p*6+3], s1 = red[p*6+4], s2v = red[p*6+5];
      const float Pv0 = CS * s0 * s0, Pv1 = CS * s1 * s1, Pv2 = CS * s2v * s2v;
      const float rp0 = __builtin_amdgcn_rcpf(P0);
      const float rp1 = __builtin_amdgcn_rcpf(P1);
      const float rp2 = __builtin_amdgcn_rcpf(P2);
      const float H0  = fmaxf(P0 - Pv0, 0.f) * rp0;
      const float H1k = fmaxf(P1 - Pv1, 0.f) * rp1;
      const float H2k = fmaxf(P2 - Pv2, 0.f) * rp2;
      const float H1m = fmaxf(P2 - Pv1, 0.f) * rp2;   // mirror: P1(m)=P2(k)
      const float H2m = fmaxf(P1 - Pv2, 0.f) * rp1;   // mirror: P2(m)=P1(k)
      // k side: gain + inverse channel DFT
      float G0r = H0 * A0r,  G0i = H0 * A0i;
      float G1r = H1k * A1r, G1i = H1k * A1i;
      float G2r = H2k * A2r, G2i = H2k * A2i;
      float Qpr = G1r + G2r, Qpi = G1i + G2i, Qmr = G1r - G2r, Qmi = G1i - G2i;
      const float M0kr = G0r + Qpr,        M0ki = G0i + Qpi;
      float u1r = G0r - 0.5f * Qpr,        u1i = G0i - 0.5f * Qpi;
      const float M1kr = u1r - S3 * Qmi,   M1ki = u1i + S3 * Qmr;
      const float M2kr = u1r + S3 * Qmi,   M2ki = u1i - S3 * Qmr;
      // m side: A0->conj(A0), A1->conj(A2), A2->conj(A1)
      G0r = H0 * A0r;   G0i = -H0 * A0i;
      G1r = H1m * A2r;  G1i = -H1m * A2i;
      G2r = H2m * A1r;  G2i = -H2m * A1i;
      Qpr = G1r + G2r;  Qpi = G1i + G2i;  Qmr = G1r - G2r;  Qmi = G1i - G2i;
      const float M0mr = G0r + Qpr,        M0mi = G0i + Qpi;
      u1r = G0r - 0.5f * Qpr;              u1i = G0i - 0.5f * Qpi;
      const float M1mr = u1r - S3 * Qmi,   M1mi = u1i + S3 * Qmr;
      const float M2mr = u1r + S3 * Qmi,   M2mi = u1i - S3 * Qmr;
      // Hermitian parts x2 (1/2 folded into epilogue 1/6144)
      const float B0r = M0kr + M0mr, B0i = M0ki - M0mi;
      const float B1r = M1kr + M1mr, B1i = M1ki - M1mi;
      B2r[lp] = M2kr + M2mr;  B2i[lp] = M2ki - M2mi;
      // pack Q = H0 + i*H1 over Z plane (task owns both k and m)
      sc[zp + ok] = __floats2half2_rn(B0r - B1i, B0i + B1r);
      sc[zp + om] = __floats2half2_rn(B0r + B1i, B1r - B0i);
    }
    // pack R = H2_{p0} + i*H2_{p1} over W plane
    sc[wp + ok] = __floats2half2_rn(B2r[0] - B2i[1], B2i[0] + B2r[1]);
    sc[wp + om] = __floats2half2_rn(B2r[0] + B2i[1], B2r[1] - B2i[0]);
  }
  __syncthreads();

  // ---- pass 3: inv ROW FFTs (kx -> x), write back to rows ------------------
  if (t < 192) {
    const int T = t >> 5, row = t & 31;
    const int rb = T * PL + row * LSTR;
    float ar[32], ai[32];
    #pragma unroll
    for (int i = 0; i < 32; ++i) {
      const __half2 z = sc[rb + REV5[i]];
      ar[i] = __low2float(z); ai[i] = __high2float(z);
    }
    fft32<+1>(ar, ai);
    #pragma unroll
    for (int i = 0; i < 32; ++i) sc[rb + i] = __floats2half2_rn(ar[i], ai[i]);
  }
  __syncthreads();

  // ---- pass 4: inv COL FFTs (ky -> y) + direct store from registers -------
  if (t < 192) {
    const int T = t >> 5, col = t & 31;
    const int cb = T * PL + col;
    float ar[32], ai[32];
    #pragma unroll
    for (int i = 0; i < 32; ++i) {
      const __half2 z = sc[cb + LSTR * REV5[i]];
      ar[i] = __low2float(z); ai[i] = __high2float(z);
    }
    fft32<+1>(ar, ai);

    const float tx = (float)col - 15.5f;
    const float wx = __expf(tx * tx * INV_WIN_DEN);

    int pA, cA, pB, cB;
    if (T < 4) { pA = T; cA = 0; pB = T; cB = 1; }
    else { const int j = T - 4; pA = 2*j; cA = 2; pB = 2*j + 1; cB = 2; }

    // ---- side A (Re) ----
    {
      const int ppy = pgeo[pA*4+0], ppx = pgeo[pA*4+1], pb = pgeo[pA*4+2];
      const int ox = ppx * 8 - 32 + col;
      if ((unsigned)ox < 512u) {
        const float mc = red[pA*6 + cA] * (1.f/1024.f);
        float* dp = (MODE == 1)
          ? dst + (size_t)pgeo[pA*4+3] * PLANE_FLOATS + ((size_t)pb * 3 + cA) * 262144 + ox
          : dst + ((size_t)pb * 3 + cA) * 262144 + ox;
        const int oy0 = ppy * 8 - 32;
        #pragma unroll
        for (int y = 0; y < 32; ++y) {
          const int oy = oy0 + y;
          if ((unsigned)oy < 512u) {
            const float wv = wx * W1C[y];
            const float val = (ar[y] * INV6144 + mc * wv) * wv;
            if (MODE == 1) dp[(size_t)oy * 512] = val;
            else           atomicAdd(&dp[(size_t)oy * 512], val);
          }
        }
      }
    }
    // ---- side B (Im) ----
    {
      const int ppy = pgeo[pB*4+0], ppx = pgeo[pB*4+1], pb = pgeo[pB*4+2];
      const int ox = ppx * 8 - 32 + col;
      if ((unsigned)ox < 512u) {
        const float mc = red[pB*6 + cB] * (1.f/1024.f);
        float* dp = (MODE == 1)
          ? dst + (size_t)pgeo[pB*4+3] * PLANE_FLOATS + ((size_t)pb * 3 + cB) * 262144 + ox
          : dst + ((size_t)pb * 3 + cB) * 262144 + ox;
        const int oy0 = ppy * 8 - 32;
        #pragma unroll
        for (int y = 0; y < 32; ++y) {
          const int oy = oy0 + y;
          if ((unsigned)oy < 512u) {
            const float wv = wx * W1C[y];
            const float val = (ai[y] * INV6144 + mc * wv) * wv;
            if (MODE == 1) dp[(size_t)oy * 512] = val;
            else           atomicAdd(&dp[(size_t)oy * 512], val);
          }
        }
      }
    }
  }
}

// mask(y,x) = mrow(y%8) * mrow(x%8), mrow(r) = sum_k w1[r+8k]^2
__device__ __forceinline__ float mask_row(int r) {
  float m = 0.f;
  #pragma unroll
  for (int k = 0; k < 4; ++k) {
    float tt = (float)(r + 8 * k) - 15.5f;
    float w = __expf(tt * tt * INV_WIN_DEN);
    m += w * w;
  }
  return m;
}

// MODE1 phase 2: out = (sum of 16 planes + eps) / (mask + eps)
__global__ void wiener_combine(const float* __restrict__ ws, float* __restrict__ out)
{
  const int i = blockIdx.x * 256 + threadIdx.x;   // out_size = 3,145,728
  const int xx = i & 511;
  const int yy = (i >> 9) & 511;
  float s = 0.f;
  #pragma unroll
  for (int p = 0; p < 16; ++p) s += ws[(size_t)p * PLANE_FLOATS + i];
  out[i] = (s + EPSF) / (mask_row(yy & 7) * mask_row(xx & 7) + EPSF);
}

// MODE0 phase 2: in-place normalize after atomic accumulation
__global__ void wiener_norm(float* __restrict__ out)
{
  const int i = blockIdx.x * 256 + threadIdx.x;
  const int xx = i & 511;
  const int yy = (i >> 9) & 511;
  out[i] = (out[i] + EPSF) / (mask_row(yy & 7) * mask_row(xx & 7) + EPSF);
}

extern "C" void kernel_launch(void* const* d_in, const int* in_sizes, int n_in,
                              void* d_out, int out_size, void* d_ws, size_t ws_size,
                              hipStream_t stream)
{
  const float* I = (const float*)d_in[0];
  const float* S = (const float*)d_in[1];
  float* out = (float*)d_out;
  const int nblocks = (4 * 67 * 67) / 4;   // 4 patches per block, 4489 blocks

  if (ws_size >= WS_NEEDED && d_ws != nullptr) {
    float* ws = (float*)d_ws;
    // every in-crop plane pixel is written exactly once -> no zeroing needed
    wiener_patch<1><<<dim3(nblocks), dim3(256), 0, stream>>>(I, S, ws);
    wiener_combine<<<dim3(out_size / 256), dim3(256), 0, stream>>>(ws, out);
  } else {
    hipMemsetAsync(out, 0, (size_t)out_size * sizeof(float), stream);
    wiener_patch<0><<<dim3(nblocks), dim3(256), 0, stream>>>(I, S, out);
    wiener_norm<<<dim3(out_size / 256), dim3(256), 0, stream>>>(out);
  }
}

// Round 9
// 147.383 us; speedup vs baseline: 2.9629x; 1.1351x over previous
//
#include <hip/hip_runtime.h>
#include <hip/hip_fp16.h>

// ---------------------------------------------------------------------------
// Wiener 3D patch filter, MI355X — packed-fp16 FFT (v_pk_*_f16), fp16 complex
// LDS, direct register->global epilogue.
// 4 patches / 256-thread block; 6 complex planes (half2, row stride 33):
//   plane p (p=0..3): Z_p = fft2(a0_p + i*a1_p)   (later reused for Q_p)
//   plane 4+j (j=0,1): W_j = fft2(a2_{2j} + i*a2_{2j+1})  (reused for R_j)
// Spectral middle (Hermitian split -> ch-DFT -> Wiener gain -> inv ch-DFT ->
// hermitianize -> repack) stays f32. Inverse passes ordered row-then-col so
// the last pass stores straight from registers.
// Overlap-add via 16 parity planes in d_ws (no atomics); atomic fallback.
// ---------------------------------------------------------------------------

constexpr float TWR[16] = {
  1.0f, 0.98078528040323044f, 0.92387953251128674f, 0.83146961230254524f,
  0.70710678118654752f, 0.55557023301960222f, 0.38268343236508977f, 0.19509032201612827f,
  0.0f, -0.19509032201612827f, -0.38268343236508977f, -0.55557023301960222f,
  -0.70710678118654752f, -0.83146961230254524f, -0.92387953251128674f, -0.98078528040323044f
};
constexpr float TWI[16] = {
  -0.0f, -0.19509032201612827f, -0.38268343236508977f, -0.55557023301960222f,
  -0.70710678118654752f, -0.83146961230254524f, -0.92387953251128674f, -0.98078528040323044f,
  -1.0f, -0.98078528040323044f, -0.92387953251128674f, -0.83146961230254524f,
  -0.70710678118654752f, -0.55557023301960222f, -0.38268343236508977f, -0.19509032201612827f
};
constexpr int REV5[32] = {0,16,8,24,4,20,12,28,2,18,10,26,6,22,14,30,
                          1,17,9,25,5,21,13,29,3,19,11,27,7,23,15,31};
// W1C[i] = exp(-(i-15.5)^2 / 76.8)
constexpr float W1C[32] = {
  0.0437942f, 0.0647235f, 0.0931963f, 0.1307451f,
  0.1787074f, 0.2379852f, 0.3087788f, 0.3903331f,
  0.4807436f, 0.5768747f, 0.6744349f, 0.7682257f,
  0.8525655f, 0.9218431f, 0.9711281f, 0.9967501f,
  0.9967501f, 0.9711281f, 0.9218431f, 0.8525655f,
  0.7682257f, 0.6744349f, 0.5768747f, 0.4807436f,
  0.3903331f, 0.3087788f, 0.2379852f, 0.1787074f,
  0.1307451f, 0.0931963f, 0.0647235f, 0.0437942f
};

constexpr float S3    = 0.86602540378443865f;  // sqrt(3)/2
constexpr float EPSF  = 1e-15f;
constexpr float INV_WIN_DEN = -1.0f / 76.8f;
constexpr float CS    = 1.1499041e-4f;         // (mean win^2)^2 / 1024
constexpr float INV6144 = 1.0f / 6144.0f;

#define PLANE_FLOATS (4 * 3 * 512 * 512)
#define WS_NEEDED    ((size_t)16 * PLANE_FLOATS * 4)
#define LSTR 33                 // row stride in half2 (= dwords), padded
#define PL   (32 * LSTR)        // complex plane = 1056 half2

// ---- packed-fp16 complex helpers ----
__device__ __forceinline__ __half2 hswap(__half2 v) {          // (im, re)
  unsigned u = __builtin_bit_cast(unsigned, v);
  u = (u << 16) | (u >> 16);
  return __builtin_bit_cast(__half2, u);
}
__device__ __forceinline__ __half2 hneg_hi(__half2 v) {        // (re, -im)
  return __builtin_bit_cast(__half2, __builtin_bit_cast(unsigned, v) ^ 0x80000000u);
}
__device__ __forceinline__ __half2 hneg_lo(__half2 v) {        // (-re, im)
  return __builtin_bit_cast(__half2, __builtin_bit_cast(unsigned, v) ^ 0x00008000u);
}

// ---- packed butterfly with compile-time twiddle specialization ----
// u' = u + w*v ; v' = u - w*v, with complex packed as half2 (lo=re, hi=im).
template<int SIGN, int K>
__device__ __forceinline__ void bflyh(__half2& u, __half2& v) {
  __half2 t;
  if constexpr (K == 0) {
    t = v;
  } else if constexpr (K == 8) {
    // fwd: w=-i -> t=(vi,-vr);  inv: w=+i -> t=(-vi,vr)
    const __half2 s = hswap(v);
    t = (SIGN < 0) ? hneg_hi(s) : hneg_lo(s);
  } else {
    const float wr = TWR[K];
    const float wi = (SIGN < 0) ? TWI[K] : -TWI[K];
    const __half2 wr2 = __float2half2_rn(wr);
    const __half2 wi2 = __halves2half2(__float2half_rn(-wi), __float2half_rn(wi));
    // t = (wr*vr - wi*vi, wr*vi + wi*vr)
    t = __hfma2(wr2, v, __hmul2(wi2, hswap(v)));
  }
  const __half2 un = __hadd2(u, t);
  v = __hsub2(u, t);
  u = un;
}

template<int SIGN, int S, int J>
__device__ __forceinline__ void stage_jh(__half2* z) {
  constexpr int m = 1 << S, h = m >> 1, ts = 32 >> S;
  if constexpr (J < h) {
    #pragma unroll
    for (int k = 0; k < 32; k += m)
      bflyh<SIGN, J * ts>(z[k + J], z[k + J + h]);
    stage_jh<SIGN, S, J + 1>(z);
  }
}

template<int SIGN>
__device__ __forceinline__ void fft32h(__half2* z) {
  stage_jh<SIGN, 1, 0>(z);
  stage_jh<SIGN, 2, 0>(z);
  stage_jh<SIGN, 3, 0>(z);
  stage_jh<SIGN, 4, 0>(z);
  stage_jh<SIGN, 5, 0>(z);
}

// reflect-pad index mapping, N=512, mode='reflect'
__device__ __forceinline__ int refl(int v) {
  v = (v < 0) ? -v : v;
  return (v >= 512) ? (1022 - v) : v;
}

// MODE 0: atomicAdd into out (fallback).  MODE 1: plain store into parity plane.
template<int MODE>
__global__ __launch_bounds__(256)
void wiener_patch(const float* __restrict__ I,
                  const float* __restrict__ Sd,
                  float* __restrict__ dst)
{
  __shared__ __half2 sc[6 * PL];   // 25,344 B
  __shared__ float red[24];        // [p*6 + {I0,I1,I2,S0,S1,S2}]
  __shared__ int   pgeo[16];       // [p*4 + {py,px,b,parity}]

  const int t  = threadIdx.x;
  const int q  = t >> 6;           // patch slot 0..3 (wave == patch)
  const int tl = t & 63;

  if (t < 4) {
    int pp = blockIdx.x * 4 + t;
    int ppx = pp % 67 + 1;  pp /= 67;
    int ppy = pp % 67 + 1;
    int pb  = pp / 67;
    pgeo[t*4+0] = ppy; pgeo[t*4+1] = ppx; pgeo[t*4+2] = pb;
    pgeo[t*4+3] = ((ppy & 3) << 2) | (ppx & 3);
  }
  __syncthreads();

  // ---- load: 64 threads/patch; (a0,a1) -> half2 Z plane, a2 -> b16 W half --
  const int py = pgeo[q*4+0], px = pgeo[q*4+1], b = pgeo[q*4+2];
  {
    float sI0=0.f,sI1=0.f,sI2=0.f,sS0=0.f,sS1=0.f,sS2=0.f;
    const int gy0 = py * 8 - 32, gx0 = px * 8 - 32;
    const int x  = tl & 31;
    const int y0 = tl >> 5;        // 0/1; rows y0+2i
    const int rx = refl(gx0 + x);
    const size_t bbase = (size_t)b * 3 * 262144;
    const int zb = q * PL;
    const int wb = (4 + (q >> 1)) * PL;
    const int par = q & 1;
    __half* scH = reinterpret_cast<__half*>(sc);
    #pragma unroll
    for (int i = 0; i < 16; ++i) {
      int y  = y0 + 2 * i;
      int ry = refl(gy0 + y);
      size_t g = bbase + (size_t)ry * 512 + rx;
      float v0 = I[g];            float u0 = Sd[g];
      float v1 = I[g + 262144];   float u1 = Sd[g + 262144];
      float v2 = I[g + 524288];   float u2 = Sd[g + 524288];
      sI0 += v0; sI1 += v1; sI2 += v2;
      sS0 += u0; sS1 += u1; sS2 += u2;
      const int l = y * LSTR + x;
      sc[zb + l] = __floats2half2_rn(v0, v1);
      scH[2 * (wb + l) + par] = __float2half_rn(v2);
    }
    #pragma unroll
    for (int off = 32; off > 0; off >>= 1) {
      sI0 += __shfl_down(sI0, off); sI1 += __shfl_down(sI1, off); sI2 += __shfl_down(sI2, off);
      sS0 += __shfl_down(sS0, off); sS1 += __shfl_down(sS1, off); sS2 += __shfl_down(sS2, off);
    }
    if (tl == 0) {                 // wave == patch: direct write, no atomics
      red[q*6+0] = sI0; red[q*6+1] = sI1; red[q*6+2] = sI2;
      red[q*6+3] = sS0; red[q*6+4] = sS1; red[q*6+5] = sS2;
    }
  }
  __syncthreads();

  // ---- pass 1: fwd row FFTs (f32 window x0.5 + mean-sub, then packed FFT) --
  if (t < 192) {
    const int T = t >> 5, row = t & 31;
    float ma, mb;
    if (T < 4) { ma = red[T*6+0] * (1.f/1024.f); mb = red[T*6+1] * (1.f/1024.f); }
    else { const int j = T - 4; ma = red[(2*j)*6+2] * (1.f/1024.f); mb = red[(2*j+1)*6+2] * (1.f/1024.f); }
    const int rb = T * PL + row * LSTR;
    const float ty = (float)row - 15.5f;
    const float hw = 0.5f * __expf(ty * ty * INV_WIN_DEN);
    __half2 z[32];
    #pragma unroll
    for (int i = 0; i < 32; ++i) {
      const int s = REV5[i];
      const __half2 zin = sc[rb + s];
      const float wv = hw * W1C[s];
      z[i] = __floats2half2_rn((__low2float(zin)  - ma) * wv,
                               (__high2float(zin) - mb) * wv);
    }
    fft32h<-1>(z);
    #pragma unroll
    for (int i = 0; i < 32; ++i) sc[rb + i] = z[i];
  }
  __syncthreads();

  // ---- pass 2: fwd col FFTs (fully packed) ---------------------------------
  if (t < 192) {
    const int T = t >> 5, col = t & 31;
    const int cb = T * PL + col;
    __half2 z[32];
    #pragma unroll
    for (int i = 0; i < 32; ++i) z[i] = sc[cb + LSTR * REV5[i]];
    fft32h<-1>(z);
    #pragma unroll
    for (int i = 0; i < 32; ++i) sc[cb + LSTR * i] = z[i];
  }
  __syncthreads();

  // ---- spectral middle (f32): mirror pairs (k, -k), bank-aware ky-walk -----
  for (int task = t; task < 1028; task += 256) {
    const int j = (task >= 514) ? 1 : 0;
    const int u = task - j * 514;
    int ky, kx;
    if (u < 480) { ky = u & 31; kx = 1 + (u >> 5); }
    else { const int e = u - 480; kx = (e >= 17) ? 16 : 0; ky = (e >= 17) ? (e - 17) : e; }
    const int my = (32 - ky) & 31, mx = (32 - kx) & 31;
    const int ok = ky * LSTR + kx, om = my * LSTR + mx;
    const int zp0 = (2 * j) * PL, zp1 = zp0 + PL, wp = (4 + j) * PL;
    const __half2 Wkh = sc[wp + ok], Wmh = sc[wp + om];
    const float Wkr = __low2float(Wkh), Wki = __high2float(Wkh);
    const float Wmr = __low2float(Wmh), Wmi = __high2float(Wmh);
    float B2r[2], B2i[2];
    #pragma unroll
    for (int lp = 0; lp < 2; ++lp) {
      const int zp = lp ? zp1 : zp0;
      const __half2 Zkh = sc[zp + ok], Zmh = sc[zp + om];
      const float Zkr = __low2float(Zkh), Zki = __high2float(Zkh);
      const float Zmr = __low2float(Zmh), Zmi = __high2float(Zmh);
      // Hermitian splits (x2 true scale; 0.5 folded into forward window)
      const float F0r = Zkr + Zmr, F0i = Zki - Zmi;
      const float F1r = Zki + Zmi, F1i = Zmr - Zkr;
      const float F2r = lp ? (Wki + Wmi) : (Wkr + Wmr);
      const float F2i = lp ? (Wmr - Wkr) : (Wki - Wmi);
      // forward channel DFT
      const float Spr = F1r + F2r, Spi = F1i + F2i, Smr = F1r - F2r, Smi = F1i - F2i;
      const float A0r = F0r + Spr,        A0i = F0i + Spi;
      const float t1r = F0r - 0.5f * Spr, t1i = F0i - 0.5f * Spi;
      const float A1r = t1r + S3 * Smi,   A1i = t1i - S3 * Smr;
      const float A2r = t1r - S3 * Smi,   A2i = t1i + S3 * Smr;
      const float P0 = A0r * A0r + A0i * A0i + EPSF;
      const float P1 = A1r * A1r + A1i * A1i + EPSF;
      const float P2 = A2r * A2r + A2i * A2i + EPSF;
      const int p = 2 * j + lp;
      const float s0 = red[p*6+3], s1 = red[p*6+4], s2v = red[p*6+5];
      const float Pv0 = CS * s0 * s0, Pv1 = CS * s1 * s1, Pv2 = CS * s2v * s2v;
      const float rp0 = __builtin_amdgcn_rcpf(P0);
      const float rp1 = __builtin_amdgcn_rcpf(P1);
      const float rp2 = __builtin_amdgcn_rcpf(P2);
      const float H0  = fmaxf(P0 - Pv0, 0.f) * rp0;
      const float H1k = fmaxf(P1 - Pv1, 0.f) * rp1;
      const float H2k = fmaxf(P2 - Pv2, 0.f) * rp2;
      const float H1m = fmaxf(P2 - Pv1, 0.f) * rp2;   // mirror: P1(m)=P2(k)
      const float H2m = fmaxf(P1 - Pv2, 0.f) * rp1;   // mirror: P2(m)=P1(k)
      // k side: gain + inverse channel DFT
      float G0r = H0 * A0r,  G0i = H0 * A0i;
      float G1r = H1k * A1r, G1i = H1k * A1i;
      float G2r = H2k * A2r, G2i = H2k * A2i;
      float Qpr = G1r + G2r, Qpi = G1i + G2i, Qmr = G1r - G2r, Qmi = G1i - G2i;
      const float M0kr = G0r + Qpr,        M0ki = G0i + Qpi;
      float u1r = G0r - 0.5f * Qpr,        u1i = G0i - 0.5f * Qpi;
      const float M1kr = u1r - S3 * Qmi,   M1ki = u1i + S3 * Qmr;
      const float M2kr = u1r + S3 * Qmi,   M2ki = u1i - S3 * Qmr;
      // m side: A0->conj(A0), A1->conj(A2), A2->conj(A1)
      G0r = H0 * A0r;   G0i = -H0 * A0i;
      G1r = H1m * A2r;  G1i = -H1m * A2i;
      G2r = H2m * A1r;  G2i = -H2m * A1i;
      Qpr = G1r + G2r;  Qpi = G1i + G2i;  Qmr = G1r - G2r;  Qmi = G1i - G2i;
      const float M0mr = G0r + Qpr,        M0mi = G0i + Qpi;
      u1r = G0r - 0.5f * Qpr;              u1i = G0i - 0.5f * Qpi;
      const float M1mr = u1r - S3 * Qmi,   M1mi = u1i + S3 * Qmr;
      const float M2mr = u1r + S3 * Qmi,   M2mi = u1i - S3 * Qmr;
      // Hermitian parts x2 (1/2 folded into epilogue 1/6144)
      const float B0r = M0kr + M0mr, B0i = M0ki - M0mi;
      const float B1r = M1kr + M1mr, B1i = M1ki - M1mi;
      B2r[lp] = M2kr + M2mr;  B2i[lp] = M2ki - M2mi;
      // pack Q = H0 + i*H1 over Z plane (task owns both k and m)
      sc[zp + ok] = __floats2half2_rn(B0r - B1i, B0i + B1r);
      sc[zp + om] = __floats2half2_rn(B0r + B1i, B1r - B0i);
    }
    // pack R = H2_{p0} + i*H2_{p1} over W plane
    sc[wp + ok] = __floats2half2_rn(B2r[0] - B2i[1], B2i[0] + B2r[1]);
    sc[wp + om] = __floats2half2_rn(B2r[0] + B2i[1], B2r[1] - B2i[0]);
  }
  __syncthreads();

  // ---- pass 3: inv ROW FFTs (kx -> x), packed, write back to rows ----------
  if (t < 192) {
    const int T = t >> 5, row = t & 31;
    const int rb = T * PL + row * LSTR;
    __half2 z[32];
    #pragma unroll
    for (int i = 0; i < 32; ++i) z[i] = sc[rb + REV5[i]];
    fft32h<+1>(z);
    #pragma unroll
    for (int i = 0; i < 32; ++i) sc[rb + i] = z[i];
  }
  __syncthreads();

  // ---- pass 4: inv COL FFTs (ky -> y), packed, direct store from regs ------
  if (t < 192) {
    const int T = t >> 5, col = t & 31;
    const int cb = T * PL + col;
    __half2 z[32];
    #pragma unroll
    for (int i = 0; i < 32; ++i) z[i] = sc[cb + LSTR * REV5[i]];
    fft32h<+1>(z);

    const float tx = (float)col - 15.5f;
    const float wx = __expf(tx * tx * INV_WIN_DEN);

    int pA, cA, pB, cB;
    if (T < 4) { pA = T; cA = 0; pB = T; cB = 1; }
    else { const int j = T - 4; pA = 2*j; cA = 2; pB = 2*j + 1; cB = 2; }

    // ---- side A (Re) ----
    {
      const int ppy = pgeo[pA*4+0], ppx = pgeo[pA*4+1], pb = pgeo[pA*4+2];
      const int ox = ppx * 8 - 32 + col;
      if ((unsigned)ox < 512u) {
        const float mc = red[pA*6 + cA] * (1.f/1024.f);
        float* dp = (MODE == 1)
          ? dst + (size_t)pgeo[pA*4+3] * PLANE_FLOATS + ((size_t)pb * 3 + cA) * 262144 + ox
          : dst + ((size_t)pb * 3 + cA) * 262144 + ox;
        const int oy0 = ppy * 8 - 32;
        #pragma unroll
        for (int y = 0; y < 32; ++y) {
          const int oy = oy0 + y;
          if ((unsigned)oy < 512u) {
            const float wv = wx * W1C[y];
            const float val = (__low2float(z[y]) * INV6144 + mc * wv) * wv;
            if (MODE == 1) dp[(size_t)oy * 512] = val;
            else           atomicAdd(&dp[(size_t)oy * 512], val);
          }
        }
      }
    }
    // ---- side B (Im) ----
    {
      const int ppy = pgeo[pB*4+0], ppx = pgeo[pB*4+1], pb = pgeo[pB*4+2];
      const int ox = ppx * 8 - 32 + col;
      if ((unsigned)ox < 512u) {
        const float mc = red[pB*6 + cB] * (1.f/1024.f);
        float* dp = (MODE == 1)
          ? dst + (size_t)pgeo[pB*4+3] * PLANE_FLOATS + ((size_t)pb * 3 + cB) * 262144 + ox
          : dst + ((size_t)pb * 3 + cB) * 262144 + ox;
        const int oy0 = ppy * 8 - 32;
        #pragma unroll
        for (int y = 0; y < 32; ++y) {
          const int oy = oy0 + y;
          if ((unsigned)oy < 512u) {
            const float wv = wx * W1C[y];
            const float val = (__high2float(z[y]) * INV6144 + mc * wv) * wv;
            if (MODE == 1) dp[(size_t)oy * 512] = val;
            else           atomicAdd(&dp[(size_t)oy * 512], val);
          }
        }
      }
    }
  }
}

// mask(y,x) = mrow(y%8) * mrow(x%8), mrow(r) = sum_k w1[r+8k]^2
__device__ __forceinline__ float mask_row(int r) {
  float m = 0.f;
  #pragma unroll
  for (int k = 0; k < 4; ++k) {
    float tt = (float)(r + 8 * k) - 15.5f;
    float w = __expf(tt * tt * INV_WIN_DEN);
    m += w * w;
  }
  return m;
}

// MODE1 phase 2: out = (sum of 16 planes + eps) / (mask + eps)
__global__ void wiener_combine(const float* __restrict__ ws, float* __restrict__ out)
{
  const int i = blockIdx.x * 256 + threadIdx.x;   // out_size = 3,145,728
  const int xx = i & 511;
  const int yy = (i >> 9) & 511;
  float s = 0.f;
  #pragma unroll
  for (int p = 0; p < 16; ++p) s += ws[(size_t)p * PLANE_FLOATS + i];
  out[i] = (s + EPSF) / (mask_row(yy & 7) * mask_row(xx & 7) + EPSF);
}

// MODE0 phase 2: in-place normalize after atomic accumulation
__global__ void wiener_norm(float* __restrict__ out)
{
  const int i = blockIdx.x * 256 + threadIdx.x;
  const int xx = i & 511;
  const int yy = (i >> 9) & 511;
  out[i] = (out[i] + EPSF) / (mask_row(yy & 7) * mask_row(xx & 7) + EPSF);
}

extern "C" void kernel_launch(void* const* d_in, const int* in_sizes, int n_in,
                              void* d_out, int out_size, void* d_ws, size_t ws_size,
                              hipStream_t stream)
{
  const float* I = (const float*)d_in[0];
  const float* S = (const float*)d_in[1];
  float* out = (float*)d_out;
  const int nblocks = (4 * 67 * 67) / 4;   // 4 patches per block, 4489 blocks

  if (ws_size >= WS_NEEDED && d_ws != nullptr) {
    float* ws = (float*)d_ws;
    // every in-crop plane pixel is written exactly once -> no zeroing needed
    wiener_patch<1><<<dim3(nblocks), dim3(256), 0, stream>>>(I, S, ws);
    wiener_combine<<<dim3(out_size / 256), dim3(256), 0, stream>>>(ws, out);
  } else {
    hipMemsetAsync(out, 0, (size_t)out_size * sizeof(float), stream);
    wiener_patch<0><<<dim3(nblocks), dim3(256), 0, stream>>>(I, S, out);
    wiener_norm<<<dim3(out_size / 256), dim3(256), 0, stream>>>(out);
  }
}

// Round 10
// 145.047 us; speedup vs baseline: 3.0106x; 1.0161x over previous
//
#include <hip/hip_runtime.h>
#include <hip/hip_fp16.h>

// ---------------------------------------------------------------------------
// Wiener 3D patch filter, MI355X — packed-fp16 FFT, fp16 complex LDS,
// float4 global loads, row-owning final pass with float4 global stores.
// 4 patches / 256-thread block; 6 complex planes (half2, row stride 33):
//   plane p (p=0..3): Z_p = fft2(a0_p + i*a1_p)   (later reused for Q_p)
//   plane 4+j (j=0,1): W_j = fft2(a2_{2j} + i*a2_{2j+1})  (reused for R_j)
// Inverse passes: col (ky->y) then row (kx->x) so the last pass holds full
// spatial rows in registers and stores straight to global as float4.
// Overlap-add via 16 parity planes in d_ws (no atomics); atomic fallback.
// ---------------------------------------------------------------------------

constexpr float TWR[16] = {
  1.0f, 0.98078528040323044f, 0.92387953251128674f, 0.83146961230254524f,
  0.70710678118654752f, 0.55557023301960222f, 0.38268343236508977f, 0.19509032201612827f,
  0.0f, -0.19509032201612827f, -0.38268343236508977f, -0.55557023301960222f,
  -0.70710678118654752f, -0.83146961230254524f, -0.92387953251128674f, -0.98078528040323044f
};
constexpr float TWI[16] = {
  -0.0f, -0.19509032201612827f, -0.38268343236508977f, -0.55557023301960222f,
  -0.70710678118654752f, -0.83146961230254524f, -0.92387953251128674f, -0.98078528040323044f,
  -1.0f, -0.98078528040323044f, -0.92387953251128674f, -0.83146961230254524f,
  -0.70710678118654752f, -0.55557023301960222f, -0.38268343236508977f, -0.19509032201612827f
};
constexpr int REV5[32] = {0,16,8,24,4,20,12,28,2,18,10,26,6,22,14,30,
                          1,17,9,25,5,21,13,29,3,19,11,27,7,23,15,31};
// W1C[i] = exp(-(i-15.5)^2 / 76.8)
constexpr float W1C[32] = {
  0.0437942f, 0.0647235f, 0.0931963f, 0.1307451f,
  0.1787074f, 0.2379852f, 0.3087788f, 0.3903331f,
  0.4807436f, 0.5768747f, 0.6744349f, 0.7682257f,
  0.8525655f, 0.9218431f, 0.9711281f, 0.9967501f,
  0.9967501f, 0.9711281f, 0.9218431f, 0.8525655f,
  0.7682257f, 0.6744349f, 0.5768747f, 0.4807436f,
  0.3903331f, 0.3087788f, 0.2379852f, 0.1787074f,
  0.1307451f, 0.0931963f, 0.0647235f, 0.0437942f
};

constexpr float S3    = 0.86602540378443865f;  // sqrt(3)/2
constexpr float EPSF  = 1e-15f;
constexpr float INV_WIN_DEN = -1.0f / 76.8f;
constexpr float CS    = 1.1499041e-4f;         // (mean win^2)^2 / 1024
constexpr float INV6144 = 1.0f / 6144.0f;

#define PLANE_FLOATS (4 * 3 * 512 * 512)
#define WS_NEEDED    ((size_t)16 * PLANE_FLOATS * 4)
#define LSTR 33                 // row stride in half2 (= dwords), padded
#define PL   (32 * LSTR)        // complex plane = 1056 half2

// ---- packed-fp16 complex helpers ----
__device__ __forceinline__ __half2 hswap(__half2 v) {          // (im, re)
  unsigned u = __builtin_bit_cast(unsigned, v);
  u = (u << 16) | (u >> 16);
  return __builtin_bit_cast(__half2, u);
}
__device__ __forceinline__ __half2 hneg_hi(__half2 v) {        // (re, -im)
  return __builtin_bit_cast(__half2, __builtin_bit_cast(unsigned, v) ^ 0x80000000u);
}
__device__ __forceinline__ __half2 hneg_lo(__half2 v) {        // (-re, im)
  return __builtin_bit_cast(__half2, __builtin_bit_cast(unsigned, v) ^ 0x00008000u);
}

// ---- packed butterfly with compile-time twiddle specialization ----
template<int SIGN, int K>
__device__ __forceinline__ void bflyh(__half2& u, __half2& v) {
  __half2 t;
  if constexpr (K == 0) {
    t = v;
  } else if constexpr (K == 8) {
    const __half2 s = hswap(v);
    t = (SIGN < 0) ? hneg_hi(s) : hneg_lo(s);
  } else {
    const float wr = TWR[K];
    const float wi = (SIGN < 0) ? TWI[K] : -TWI[K];
    const __half2 wr2 = __float2half2_rn(wr);
    const __half2 wi2 = __halves2half2(__float2half_rn(-wi), __float2half_rn(wi));
    t = __hfma2(wr2, v, __hmul2(wi2, hswap(v)));
  }
  const __half2 un = __hadd2(u, t);
  v = __hsub2(u, t);
  u = un;
}

template<int SIGN, int S, int J>
__device__ __forceinline__ void stage_jh(__half2* z) {
  constexpr int m = 1 << S, h = m >> 1, ts = 32 >> S;
  if constexpr (J < h) {
    #pragma unroll
    for (int k = 0; k < 32; k += m)
      bflyh<SIGN, J * ts>(z[k + J], z[k + J + h]);
    stage_jh<SIGN, S, J + 1>(z);
  }
}

template<int SIGN>
__device__ __forceinline__ void fft32h(__half2* z) {
  stage_jh<SIGN, 1, 0>(z);
  stage_jh<SIGN, 2, 0>(z);
  stage_jh<SIGN, 3, 0>(z);
  stage_jh<SIGN, 4, 0>(z);
  stage_jh<SIGN, 5, 0>(z);
}

// reflect-pad index mapping, N=512, mode='reflect'
__device__ __forceinline__ int refl(int v) {
  v = (v < 0) ? -v : v;
  return (v >= 512) ? (1022 - v) : v;
}

// MODE 0: atomicAdd into out (fallback).  MODE 1: plain store into parity plane.
template<int MODE>
__global__ __launch_bounds__(256)
void wiener_patch(const float* __restrict__ I,
                  const float* __restrict__ Sd,
                  float* __restrict__ dst)
{
  __shared__ __half2 sc[6 * PL];   // 25,344 B
  __shared__ float red[24];        // [p*6 + {I0,I1,I2,S0,S1,S2}]
  __shared__ int   pgeo[16];       // [p*4 + {py,px,b,parity}]

  const int t  = threadIdx.x;
  const int q  = t >> 6;           // patch slot 0..3 (wave == patch)
  const int tl = t & 63;

  if (t < 4) {
    int pp = blockIdx.x * 4 + t;
    int ppx = pp % 67 + 1;  pp /= 67;
    int ppy = pp % 67 + 1;
    int pb  = pp / 67;
    pgeo[t*4+0] = ppy; pgeo[t*4+1] = ppx; pgeo[t*4+2] = pb;
    pgeo[t*4+3] = ((ppy & 3) << 2) | (ppx & 3);
  }
  __syncthreads();

  // ---- load: 64 threads/patch; (a0,a1) -> half2 Z plane, a2 -> b16 W half --
  const int py = pgeo[q*4+0], px = pgeo[q*4+1], b = pgeo[q*4+2];
  {
    float sI0=0.f,sI1=0.f,sI2=0.f,sS0=0.f,sS1=0.f,sS2=0.f;
    const int gy0 = py * 8 - 32, gx0 = px * 8 - 32;
    const size_t bbase = (size_t)b * 3 * 262144;
    const int zb = q * PL;
    const int wb = (4 + (q >> 1)) * PL;
    const int par = q & 1;
    __half* scH = reinterpret_cast<__half*>(sc);

    if (gx0 >= 0 && gx0 <= 480) {
      // interior in x: float4 loads (wave-uniform branch)
      const int c4 = (tl & 7) * 4, r0 = tl >> 3;     // 8 float4-cols x 8 rows
      #pragma unroll
      for (int i = 0; i < 4; ++i) {
        const int y  = r0 + 8 * i;
        const int ry = refl(gy0 + y);
        const size_t g = bbase + (size_t)ry * 512 + gx0 + c4;
        const float4 f0 = *reinterpret_cast<const float4*>(&I[g]);
        const float4 f1 = *reinterpret_cast<const float4*>(&I[g + 262144]);
        const float4 f2 = *reinterpret_cast<const float4*>(&I[g + 524288]);
        const float4 u0 = *reinterpret_cast<const float4*>(&Sd[g]);
        const float4 u1 = *reinterpret_cast<const float4*>(&Sd[g + 262144]);
        const float4 u2 = *reinterpret_cast<const float4*>(&Sd[g + 524288]);
        sI0 += f0.x + f0.y + f0.z + f0.w;
        sI1 += f1.x + f1.y + f1.z + f1.w;
        sI2 += f2.x + f2.y + f2.z + f2.w;
        sS0 += u0.x + u0.y + u0.z + u0.w;
        sS1 += u1.x + u1.y + u1.z + u1.w;
        sS2 += u2.x + u2.y + u2.z + u2.w;
        const int l = y * LSTR + c4;
        sc[zb + l + 0] = __floats2half2_rn(f0.x, f1.x);
        sc[zb + l + 1] = __floats2half2_rn(f0.y, f1.y);
        sc[zb + l + 2] = __floats2half2_rn(f0.z, f1.z);
        sc[zb + l + 3] = __floats2half2_rn(f0.w, f1.w);
        scH[2 * (wb + l + 0) + par] = __float2half_rn(f2.x);
        scH[2 * (wb + l + 1) + par] = __float2half_rn(f2.y);
        scH[2 * (wb + l + 2) + par] = __float2half_rn(f2.z);
        scH[2 * (wb + l + 3) + par] = __float2half_rn(f2.w);
      }
    } else {
      // border in x: scalar reflect path
      const int x  = tl & 31;
      const int y0 = tl >> 5;      // 0/1; rows y0+2i
      const int rx = refl(gx0 + x);
      #pragma unroll
      for (int i = 0; i < 16; ++i) {
        const int y  = y0 + 2 * i;
        const int ry = refl(gy0 + y);
        const size_t g = bbase + (size_t)ry * 512 + rx;
        const float v0 = I[g];            const float u0 = Sd[g];
        const float v1 = I[g + 262144];   const float u1 = Sd[g + 262144];
        const float v2 = I[g + 524288];   const float u2 = Sd[g + 524288];
        sI0 += v0; sI1 += v1; sI2 += v2;
        sS0 += u0; sS1 += u1; sS2 += u2;
        const int l = y * LSTR + x;
        sc[zb + l] = __floats2half2_rn(v0, v1);
        scH[2 * (wb + l) + par] = __float2half_rn(v2);
      }
    }
    #pragma unroll
    for (int off = 32; off > 0; off >>= 1) {
      sI0 += __shfl_down(sI0, off); sI1 += __shfl_down(sI1, off); sI2 += __shfl_down(sI2, off);
      sS0 += __shfl_down(sS0, off); sS1 += __shfl_down(sS1, off); sS2 += __shfl_down(sS2, off);
    }
    if (tl == 0) {                 // wave == patch: direct write, no atomics
      red[q*6+0] = sI0; red[q*6+1] = sI1; red[q*6+2] = sI2;
      red[q*6+3] = sS0; red[q*6+4] = sS1; red[q*6+5] = sS2;
    }
  }
  __syncthreads();

  // ---- pass 1: fwd row FFTs (f32 window x0.5 + mean-sub, then packed FFT) --
  if (t < 192) {
    const int T = t >> 5, row = t & 31;
    float ma, mb;
    if (T < 4) { ma = red[T*6+0] * (1.f/1024.f); mb = red[T*6+1] * (1.f/1024.f); }
    else { const int j = T - 4; ma = red[(2*j)*6+2] * (1.f/1024.f); mb = red[(2*j+1)*6+2] * (1.f/1024.f); }
    const int rb = T * PL + row * LSTR;
    const float ty = (float)row - 15.5f;
    const float hw = 0.5f * __expf(ty * ty * INV_WIN_DEN);
    __half2 z[32];
    #pragma unroll
    for (int i = 0; i < 32; ++i) {
      const int s = REV5[i];
      const __half2 zin = sc[rb + s];
      const float wv = hw * W1C[s];
      z[i] = __floats2half2_rn((__low2float(zin)  - ma) * wv,
                               (__high2float(zin) - mb) * wv);
    }
    fft32h<-1>(z);
    #pragma unroll
    for (int i = 0; i < 32; ++i) sc[rb + i] = z[i];
  }
  __syncthreads();

  // ---- pass 2: fwd col FFTs (fully packed) ---------------------------------
  if (t < 192) {
    const int T = t >> 5, col = t & 31;
    const int cb = T * PL + col;
    __half2 z[32];
    #pragma unroll
    for (int i = 0; i < 32; ++i) z[i] = sc[cb + LSTR * REV5[i]];
    fft32h<-1>(z);
    #pragma unroll
    for (int i = 0; i < 32; ++i) sc[cb + LSTR * i] = z[i];
  }
  __syncthreads();

  // ---- spectral middle (f32): mirror pairs (k, -k), bank-aware ky-walk -----
  for (int task = t; task < 1028; task += 256) {
    const int j = (task >= 514) ? 1 : 0;
    const int u = task - j * 514;
    int ky, kx;
    if (u < 480) { ky = u & 31; kx = 1 + (u >> 5); }
    else { const int e = u - 480; kx = (e >= 17) ? 16 : 0; ky = (e >= 17) ? (e - 17) : e; }
    const int my = (32 - ky) & 31, mx = (32 - kx) & 31;
    const int ok = ky * LSTR + kx, om = my * LSTR + mx;
    const int zp0 = (2 * j) * PL, zp1 = zp0 + PL, wp = (4 + j) * PL;
    const __half2 Wkh = sc[wp + ok], Wmh = sc[wp + om];
    const float Wkr = __low2float(Wkh), Wki = __high2float(Wkh);
    const float Wmr = __low2float(Wmh), Wmi = __high2float(Wmh);
    float B2r[2], B2i[2];
    #pragma unroll
    for (int lp = 0; lp < 2; ++lp) {
      const int zp = lp ? zp1 : zp0;
      const __half2 Zkh = sc[zp + ok], Zmh = sc[zp + om];
      const float Zkr = __low2float(Zkh), Zki = __high2float(Zkh);
      const float Zmr = __low2float(Zmh), Zmi = __high2float(Zmh);
      const float F0r = Zkr + Zmr, F0i = Zki - Zmi;
      const float F1r = Zki + Zmi, F1i = Zmr - Zkr;
      const float F2r = lp ? (Wki + Wmi) : (Wkr + Wmr);
      const float F2i = lp ? (Wmr - Wkr) : (Wki - Wmi);
      const float Spr = F1r + F2r, Spi = F1i + F2i, Smr = F1r - F2r, Smi = F1i - F2i;
      const float A0r = F0r + Spr,        A0i = F0i + Spi;
      const float t1r = F0r - 0.5f * Spr, t1i = F0i - 0.5f * Spi;
      const float A1r = t1r + S3 * Smi,   A1i = t1i - S3 * Smr;
      const float A2r = t1r - S3 * Smi,   A2i = t1i + S3 * Smr;
      const float P0 = A0r * A0r + A0i * A0i + EPSF;
      const float P1 = A1r * A1r + A1i * A1i + EPSF;
      const float P2 = A2r * A2r + A2i * A2i + EPSF;
      const int p = 2 * j + lp;
      const float s0 = red[p*6+3], s1 = red[p*6+4], s2v = red[p*6+5];
      const float Pv0 = CS * s0 * s0, Pv1 = CS * s1 * s1, Pv2 = CS * s2v * s2v;
      const float rp0 = __builtin_amdgcn_rcpf(P0);
      const float rp1 = __builtin_amdgcn_rcpf(P1);
      const float rp2 = __builtin_amdgcn_rcpf(P2);
      const float H0  = fmaxf(P0 - Pv0, 0.f) * rp0;
      const float H1k = fmaxf(P1 - Pv1, 0.f) * rp1;
      const float H2k = fmaxf(P2 - Pv2, 0.f) * rp2;
      const float H1m = fmaxf(P2 - Pv1, 0.f) * rp2;   // mirror: P1(m)=P2(k)
      const float H2m = fmaxf(P1 - Pv2, 0.f) * rp1;   // mirror: P2(m)=P1(k)
      float G0r = H0 * A0r,  G0i = H0 * A0i;
      float G1r = H1k * A1r, G1i = H1k * A1i;
      float G2r = H2k * A2r, G2i = H2k * A2i;
      float Qpr = G1r + G2r, Qpi = G1i + G2i, Qmr = G1r - G2r, Qmi = G1i - G2i;
      const float M0kr = G0r + Qpr,        M0ki = G0i + Qpi;
      float u1r = G0r - 0.5f * Qpr,        u1i = G0i - 0.5f * Qpi;
      const float M1kr = u1r - S3 * Qmi,   M1ki = u1i + S3 * Qmr;
      const float M2kr = u1r + S3 * Qmi,   M2ki = u1i - S3 * Qmr;
      G0r = H0 * A0r;   G0i = -H0 * A0i;
      G1r = H1m * A2r;  G1i = -H1m * A2i;
      G2r = H2m * A1r;  G2i = -H2m * A1i;
      Qpr = G1r + G2r;  Qpi = G1i + G2i;  Qmr = G1r - G2r;  Qmi = G1i - G2i;
      const float M0mr = G0r + Qpr,        M0mi = G0i + Qpi;
      u1r = G0r - 0.5f * Qpr;              u1i = G0i - 0.5f * Qpi;
      const float M1mr = u1r - S3 * Qmi,   M1mi = u1i + S3 * Qmr;
      const float M2mr = u1r + S3 * Qmi,   M2mi = u1i - S3 * Qmr;
      const float B0r = M0kr + M0mr, B0i = M0ki - M0mi;
      const float B1r = M1kr + M1mr, B1i = M1ki - M1mi;
      B2r[lp] = M2kr + M2mr;  B2i[lp] = M2ki - M2mi;
      sc[zp + ok] = __floats2half2_rn(B0r - B1i, B0i + B1r);
      sc[zp + om] = __floats2half2_rn(B0r + B1i, B1r - B0i);
    }
    sc[wp + ok] = __floats2half2_rn(B2r[0] - B2i[1], B2i[0] + B2r[1]);
    sc[wp + om] = __floats2half2_rn(B2r[0] + B2i[1], B2r[1] - B2i[0]);
  }
  __syncthreads();

  // ---- pass 3: inv COL FFTs (ky -> y), packed, write back to cols ----------
  if (t < 192) {
    const int T = t >> 5, col = t & 31;
    const int cb = T * PL + col;
    __half2 z[32];
    #pragma unroll
    for (int i = 0; i < 32; ++i) z[i] = sc[cb + LSTR * REV5[i]];
    fft32h<+1>(z);
    #pragma unroll
    for (int i = 0; i < 32; ++i) sc[cb + LSTR * i] = z[i];
  }
  __syncthreads();

  // ---- pass 4: inv ROW FFTs (kx -> x), packed, float4 store from regs ------
  if (t < 192) {
    const int T = t >> 5, row = t & 31;
    const int rb = T * PL + row * LSTR;
    __half2 z[32];
    #pragma unroll
    for (int i = 0; i < 32; ++i) z[i] = sc[rb + REV5[i]];
    fft32h<+1>(z);

    const float ty = (float)row - 15.5f;
    const float wy = __expf(ty * ty * INV_WIN_DEN);

    int pA, cA, pB, cB;
    if (T < 4) { pA = T; cA = 0; pB = T; cB = 1; }
    else { const int j = T - 4; pA = 2*j; cA = 2; pB = 2*j + 1; cB = 2; }

    #pragma unroll
    for (int side = 0; side < 2; ++side) {
      const int p = side ? pB : pA;
      const int c = side ? cB : cA;
      const int ppy = pgeo[p*4+0], ppx = pgeo[p*4+1], pb = pgeo[p*4+2];
      const int oy = ppy * 8 - 32 + row;
      if ((unsigned)oy < 512u) {
        const float mc = red[p*6 + c] * (1.f/1024.f);
        float* dp = (MODE == 1)
          ? dst + (size_t)pgeo[p*4+3] * PLANE_FLOATS + (((size_t)pb * 3 + c) * 512 + oy) * 512
          : dst + (((size_t)pb * 3 + c) * 512 + oy) * 512;
        const int ox0 = ppx * 8 - 32;
        #pragma unroll
        for (int k = 0; k < 8; ++k) {
          const int ox = ox0 + 4 * k;
          if ((unsigned)ox < 512u) {     // ox%4==0 -> segment fully in
            float4 v;
            float* ve = reinterpret_cast<float*>(&v);
            #pragma unroll
            for (int e = 0; e < 4; ++e) {
              const int xx = 4 * k + e;
              const float wv = wy * W1C[xx];
              const float raw = side ? __high2float(z[xx]) : __low2float(z[xx]);
              ve[e] = (raw * INV6144 + mc * wv) * wv;
            }
            if (MODE == 1) *reinterpret_cast<float4*>(dp + ox) = v;
            else {
              atomicAdd(dp + ox + 0, v.x); atomicAdd(dp + ox + 1, v.y);
              atomicAdd(dp + ox + 2, v.z); atomicAdd(dp + ox + 3, v.w);
            }
          }
        }
      }
    }
  }
}

// mask(y,x) = mrow(y%8) * mrow(x%8), mrow(r) = sum_k w1[r+8k]^2
__device__ __forceinline__ float mask_row(int r) {
  float m = 0.f;
  #pragma unroll
  for (int k = 0; k < 4; ++k) {
    float tt = (float)(r + 8 * k) - 15.5f;
    float w = __expf(tt * tt * INV_WIN_DEN);
    m += w * w;
  }
  return m;
}

// MODE1 phase 2: out = (sum of 16 planes + eps) / (mask + eps); 4 px/thread
__global__ void wiener_combine(const float* __restrict__ ws, float* __restrict__ out)
{
  const int i4 = (blockIdx.x * 256 + threadIdx.x) * 4;   // out_size = 3,145,728
  float4 s = make_float4(0.f, 0.f, 0.f, 0.f);
  #pragma unroll
  for (int p = 0; p < 16; ++p) {
    const float4 v = *reinterpret_cast<const float4*>(&ws[(size_t)p * PLANE_FLOATS + i4]);
    s.x += v.x; s.y += v.y; s.z += v.z; s.w += v.w;
  }
  const int yy = (i4 >> 9) & 511;
  const float my = mask_row(yy & 7);
  float4 o;
  o.x = (s.x + EPSF) / (my * mask_row((i4 + 0) & 7) + EPSF);
  o.y = (s.y + EPSF) / (my * mask_row((i4 + 1) & 7) + EPSF);
  o.z = (s.z + EPSF) / (my * mask_row((i4 + 2) & 7) + EPSF);
  o.w = (s.w + EPSF) / (my * mask_row((i4 + 3) & 7) + EPSF);
  *reinterpret_cast<float4*>(&out[i4]) = o;
}

// MODE0 phase 2: in-place normalize after atomic accumulation
__global__ void wiener_norm(float* __restrict__ out)
{
  const int i = blockIdx.x * 256 + threadIdx.x;
  const int xx = i & 511;
  const int yy = (i >> 9) & 511;
  out[i] = (out[i] + EPSF) / (mask_row(yy & 7) * mask_row(xx & 7) + EPSF);
}

extern "C" void kernel_launch(void* const* d_in, const int* in_sizes, int n_in,
                              void* d_out, int out_size, void* d_ws, size_t ws_size,
                              hipStream_t stream)
{
  const float* I = (const float*)d_in[0];
  const float* S = (const float*)d_in[1];
  float* out = (float*)d_out;
  const int nblocks = (4 * 67 * 67) / 4;   // 4 patches per block, 4489 blocks

  if (ws_size >= WS_NEEDED && d_ws != nullptr) {
    float* ws = (float*)d_ws;
    // every in-crop plane pixel is written exactly once -> no zeroing needed
    wiener_patch<1><<<dim3(nblocks), dim3(256), 0, stream>>>(I, S, ws);
    wiener_combine<<<dim3(out_size / 1024), dim3(256), 0, stream>>>(ws, out);
  } else {
    hipMemsetAsync(out, 0, (size_t)out_size * sizeof(float), stream);
    wiener_patch<0><<<dim3(nblocks), dim3(256), 0, stream>>>(I, S, out);
    wiener_norm<<<dim3(out_size / 256), dim3(256), 0, stream>>>(out);
  }
}